// Round 12
// baseline (176.670 us; speedup 1.0000x reference)
//
#include <hip/hip_runtime.h>
#include <math.h>

typedef __attribute__((ext_vector_type(4))) float f32x4;
typedef __attribute__((ext_vector_type(8))) short bf16x8;
typedef __attribute__((ext_vector_type(8))) unsigned short u16x8;

#define DIM 1024
#define SEQ 2048
#define NHEADS 16
#define DH 64

__device__ __forceinline__ unsigned short f2bf(float f) {
    unsigned int u = __builtin_bit_cast(unsigned int, f);
    u += 0x7fffu + ((u >> 16) & 1u);
    return (unsigned short)(u >> 16);
}

__device__ __forceinline__ float bf2f(unsigned short s) {
    unsigned int u = (unsigned int)s << 16;
    return __builtin_bit_cast(float, u);
}

__device__ __forceinline__ unsigned int cvt_pk_bf16(float lo, float hi) {
    unsigned int r;
    asm("v_cvt_pk_bf16_f32 %0, %1, %2" : "=v"(r) : "v"(lo), "v"(hi));
    return r;
}

__device__ __forceinline__ float fexp2(float x) {
    float r;
    asm("v_exp_f32 %0, %1" : "=v"(r) : "v"(x));
    return r;
}

__device__ __forceinline__ void gld16(const unsigned short* g, unsigned short* l) {
    __builtin_amdgcn_global_load_lds((const __attribute__((address_space(1))) void*)g,
                                     (__attribute__((address_space(3))) void*)l, 16, 0, 0);
}

// ---------- weight transposes (z=0..3) + LayerNorm1 (z=4) in one launch ----------
__global__ __launch_bounds__(256) void wtrans_ln(const float* __restrict__ wq,
                                                 const float* __restrict__ wo,
                                                 const float* __restrict__ wf1,
                                                 const float* __restrict__ wf2,
                                                 unsigned short* __restrict__ oq,
                                                 unsigned short* __restrict__ oo,
                                                 unsigned short* __restrict__ of1,
                                                 unsigned short* __restrict__ of2, float sc,
                                                 const float* __restrict__ x,
                                                 const float* __restrict__ g1,
                                                 const float* __restrict__ bt1,
                                                 unsigned short* __restrict__ xl) {
    int z = blockIdx.z;
    int bxi = blockIdx.x;
    int tid = threadIdx.x;
    if (z == 4) {  // LayerNorm over x rows
        int row = blockIdx.y * 128 + bxi;
        const float4* xr = (const float4*)(x + (size_t)row * DIM);
        float4 v = xr[tid];
        float s1 = v.x + v.y + v.z + v.w;
        float s2 = v.x * v.x + v.y * v.y + v.z * v.z + v.w * v.w;
#pragma unroll
        for (int m = 32; m >= 1; m >>= 1) {
            s1 += __shfl_xor(s1, m);
            s2 += __shfl_xor(s2, m);
        }
        __shared__ float r1[4], r2[4];
        int w = tid >> 6;
        if ((tid & 63) == 0) { r1[w] = s1; r2[w] = s2; }
        __syncthreads();
        s1 = r1[0] + r1[1] + r1[2] + r1[3];
        s2 = r2[0] + r2[1] + r2[2] + r2[3];
        float mu = s1 * (1.0f / DIM);
        float var = s2 * (1.0f / DIM) - mu * mu;
        float rstd = rsqrtf(var + 1e-5f);
        float4 g4 = ((const float4*)g1)[tid];
        float4 b4 = ((const float4*)bt1)[tid];
        ushort4 ov;
        ov.x = f2bf((v.x - mu) * rstd * g4.x + b4.x);
        ov.y = f2bf((v.y - mu) * rstd * g4.y + b4.y);
        ov.z = f2bf((v.z - mu) * rstd * g4.z + b4.z);
        ov.w = f2bf((v.w - mu) * rstd * g4.w + b4.w);
        *(ushort4*)(xl + (size_t)row * DIM + tid * 4) = ov;
        return;
    }
    if (bxi >= (z == 0 ? 96 : 32)) return;
    const float* w = z == 0 ? wq : z == 1 ? wo : z == 2 ? wf1 : wf2;
    unsigned short* wt = z == 0 ? oq : z == 1 ? oo : z == 2 ? of1 : of2;
    int N = z == 0 ? 3072 : 1024;
    int scale_n = z == 0 ? 1024 : 0;
    const int K = 1024;
    __shared__ float t[32][33];
    int n0 = bxi * 32, k0 = blockIdx.y * 32;
    int c = tid & 31, rb = tid >> 5;
#pragma unroll
    for (int i = 0; i < 4; ++i) {
        int r = rb + i * 8;
        t[r][c] = w[(size_t)(k0 + r) * N + n0 + c];
    }
    __syncthreads();
#pragma unroll
    for (int i = 0; i < 4; ++i) {
        int r = rb + i * 8;  // N-local
        float v = t[c][r];
        if (n0 + r < scale_n) v *= sc;
        wt[(size_t)(n0 + r) * K + k0 + c] = f2bf(v);
    }
}

// ---------- LayerNorm: bf16 in -> bf16 out ----------
__global__ __launch_bounds__(256) void ln_bf16(const unsigned short* __restrict__ x,
                                               const float* __restrict__ g,
                                               const float* __restrict__ bt,
                                               unsigned short* __restrict__ o) {
    int row = blockIdx.x, tid = threadIdx.x;
    ushort4 v4 = *(const ushort4*)(x + (size_t)row * DIM + tid * 4);
    float vx = bf2f(v4.x), vy = bf2f(v4.y), vz = bf2f(v4.z), vw = bf2f(v4.w);
    float s1 = vx + vy + vz + vw;
    float s2 = vx * vx + vy * vy + vz * vz + vw * vw;
#pragma unroll
    for (int m = 32; m >= 1; m >>= 1) {
        s1 += __shfl_xor(s1, m);
        s2 += __shfl_xor(s2, m);
    }
    __shared__ float r1[4], r2[4];
    int w = tid >> 6;
    if ((tid & 63) == 0) { r1[w] = s1; r2[w] = s2; }
    __syncthreads();
    s1 = r1[0] + r1[1] + r1[2] + r1[3];
    s2 = r2[0] + r2[1] + r2[2] + r2[3];
    float mu = s1 * (1.0f / DIM);
    float var = s2 * (1.0f / DIM) - mu * mu;
    float rstd = rsqrtf(var + 1e-5f);
    float4 g4 = ((const float4*)g)[tid];
    float4 b4 = ((const float4*)bt)[tid];
    ushort4 ov;
    ov.x = f2bf((vx - mu) * rstd * g4.x + b4.x);
    ov.y = f2bf((vy - mu) * rstd * g4.y + b4.y);
    ov.z = f2bf((vz - mu) * rstd * g4.z + b4.z);
    ov.w = f2bf((vw - mu) * rstd * g4.w + b4.w);
    *(ushort4*)(o + (size_t)row * DIM + tid * 4) = ov;
}

// ---------- GEMM, 3-buffer counted-vmcnt pipeline, XOR-swizzled LDS ----------
// C[M,N] = A[M,K](bf16) @ BT[N,K](bf16)^T. BM=128.
// VT=1: blocks with col0>=2048 write sigma-permuted transposed V to vt instead of C.
// RESID: 0=none, 1=f32 resid, 2=bf16 resid.
template <int BN, int BK, int OBF, int BIAS, int GELU_, int RESID, int VT>
__global__ __launch_bounds__(256) void gemm_kernel(const unsigned short* __restrict__ A,
                                                   const unsigned short* __restrict__ BT,
                                                   void* __restrict__ C,
                                                   const float* __restrict__ bias,
                                                   const void* __restrict__ resid,
                                                   unsigned short* __restrict__ vt,
                                                   int M, int N, int K, int nbx) {
    constexpr int U = BK / 8;              // 16B units per row
    constexpr int NAU = 128 * U;           // A-tile units
    constexpr int NBU = BN * U;            // B-tile units
    constexpr int PT = (NAU + NBU) / 256;  // gld16 per thread per stage
    constexpr int NJ = BN / 32;
    constexpr int KK = BK / 32;
    extern __shared__ char smem[];
    unsigned short* As = (unsigned short*)smem;      // [3][128*BK]
    unsigned short* Bs = As + 3 * 128 * BK;          // [3][BN*BK]
    int tid = threadIdx.x;
    int lane = tid & 63, w = tid >> 6;
    int l15 = lane & 15, lhi = lane >> 4;
    int nwg = gridDim.x, wg = blockIdx.x;
    int swz = (wg & 7) * (nwg >> 3) + (wg >> 3);  // XCD-chunked (nwg % 8 == 0)
    int bx = swz % nbx, by = swz / nbx;
    int row0 = by * 128, col0 = bx * BN;
    int wrow = (w >> 1) * 64, wcol = (w & 1) * (16 * NJ);
    f32x4 zero = {0.f, 0.f, 0.f, 0.f};
    f32x4 acc[4][NJ];
#pragma unroll
    for (int i = 0; i < 4; ++i)
#pragma unroll
        for (int j = 0; j < NJ; ++j) acc[i][j] = zero;
    auto stage = [&](int buf, int kt) {
#pragma unroll
        for (int p = 0; p < PT; ++p) {
            if (p * 256 < NAU) {
                int u = tid + p * 256;
                int r = u / U, cu = u % U;
                int scu = cu ^ (r & (U - 1));
                gld16(A + (size_t)(row0 + r) * K + kt * BK + scu * 8, As + buf * 128 * BK + u * 8);
            } else {
                int ub = tid + p * 256 - NAU;
                int r = ub / U, cu = ub % U;
                int scu = cu ^ (r & (U - 1));
                gld16(BT + (size_t)(col0 + r) * K + kt * BK + scu * 8, Bs + buf * BN * BK + ub * 8);
            }
        }
    };
    int nk = K / BK;
    stage(0, 0);
    stage(1, 1);
    asm volatile("s_waitcnt vmcnt(%0)" ::"i"(PT) : "memory");
    __builtin_amdgcn_s_barrier();
    __builtin_amdgcn_sched_barrier(0);
    int cur = 0;
    for (int kt = 0; kt < nk; ++kt) {
        int nxt2 = cur + 2 >= 3 ? cur - 1 : cur + 2;
        if (kt + 2 < nk) stage(nxt2, kt + 2);
        const unsigned short* Ab = As + cur * 128 * BK;
        const unsigned short* Bb = Bs + cur * BN * BK;
        bf16x8 af[4][KK], bfr[NJ][KK];
#pragma unroll
        for (int i = 0; i < 4; ++i)
#pragma unroll
            for (int kk = 0; kk < KK; ++kk) {
                int rr = wrow + i * 16 + l15;
                int up = (kk * 4 + lhi) ^ (rr & (U - 1));
                af[i][kk] = *(const bf16x8*)&Ab[rr * BK + up * 8];
            }
#pragma unroll
        for (int j = 0; j < NJ; ++j)
#pragma unroll
            for (int kk = 0; kk < KK; ++kk) {
                int rr = wcol + j * 16 + l15;
                int up = (kk * 4 + lhi) ^ (rr & (U - 1));
                bfr[j][kk] = *(const bf16x8*)&Bb[rr * BK + up * 8];
            }
#pragma unroll
        for (int kk = 0; kk < KK; ++kk)
#pragma unroll
            for (int i = 0; i < 4; ++i)
#pragma unroll
                for (int j = 0; j < NJ; ++j)
                    acc[i][j] = __builtin_amdgcn_mfma_f32_16x16x32_bf16(af[i][kk], bfr[j][kk],
                                                                        acc[i][j], 0, 0, 0);
        __builtin_amdgcn_sched_barrier(0);
        if (kt + 1 < nk) {
            if (kt + 2 < nk)
                asm volatile("s_waitcnt vmcnt(%0)" ::"i"(PT) : "memory");
            else
                asm volatile("s_waitcnt vmcnt(0)" ::: "memory");
            __builtin_amdgcn_s_barrier();
            __builtin_amdgcn_sched_barrier(0);
        }
        cur = cur + 1 == 3 ? 0 : cur + 1;
    }
    if (VT && col0 >= 2048) {
        // V block: transpose + sigma-permute into vt[b,h][d][n]; skip normal C write.
        __syncthreads();  // all waves done with staging LDS
        unsigned short* Ct = (unsigned short*)smem;  // [128][130] bf16 (33280 B)
#pragma unroll
        for (int i = 0; i < 4; ++i)
#pragma unroll
            for (int j = 0; j < NJ; ++j)
#pragma unroll
                for (int r = 0; r < 4; ++r)
                    Ct[(wrow + i * 16 + lhi * 4 + r) * 130 + (wcol + j * 16 + l15)] =
                        f2bf(acc[i][j][r]);
        __syncthreads();
        int l = tid & 63, wv = tid >> 6;
        int sig = (l & 32) | ((l & 4) << 2) | ((l & 24) >> 1) | (l & 3);
        int b = row0 >> 11, n0 = row0 & 2047;
        int h0 = (col0 - 2048) >> 6;
        for (int c = wv * 64; c < wv * 64 + 64; ++c) {
            int ntl = c & 1, hl = (c >> 1) & 1, d = c >> 2;
            unsigned short v = Ct[(ntl * 64 + sig) * 130 + hl * 64 + d];
            vt[((size_t)(b * NHEADS + h0 + hl) * DH + d) * SEQ + n0 + ntl * 64 + l] = v;
        }
        return;
    }
#pragma unroll
    for (int i = 0; i < 4; ++i)
#pragma unroll
        for (int j = 0; j < NJ; ++j)
#pragma unroll
            for (int r = 0; r < 4; ++r) {
                int row = row0 + wrow + i * 16 + lhi * 4 + r;
                int col = col0 + wcol + j * 16 + l15;
                float v = acc[i][j][r];
                if (BIAS) v += bias[col];
                if (GELU_) v = 0.5f * v * (1.0f + erff(v * 0.70710678118f));
                if (RESID == 1) v += ((const float*)resid)[(size_t)row * N + col];
                if (RESID == 2) v += bf2f(((const unsigned short*)resid)[(size_t)row * N + col]);
                if (OBF)
                    ((unsigned short*)C)[(size_t)row * N + col] = f2bf(v);
                else
                    ((float*)C)[(size_t)row * N + col] = v;
            }
}

// ---------- out-proj GEMM with fused split-K combine in A-staging ----------
// A = (po0+po1)/(l0+l1) [reg-staged], B = woutT; epilogue: +b_out +x(f32) -> outb bf16.
__global__ __launch_bounds__(256) void gemm_oproj(const unsigned short* __restrict__ po,
                                                  const float* __restrict__ pl,
                                                  const unsigned short* __restrict__ BT,
                                                  unsigned short* __restrict__ outb,
                                                  const float* __restrict__ bias,
                                                  const float* __restrict__ xres) {
    constexpr int BK = 64, BN = 64, U = 8, NJ = 2, KK = 2, nk = 16;
    __shared__ unsigned short As[2][128 * 64];
    __shared__ unsigned short Bs[2][64 * 64];
    int tid = threadIdx.x;
    int lane = tid & 63, w = tid >> 6;
    int l15 = lane & 15, lhi = lane >> 4;
    int nwg = gridDim.x, wg = blockIdx.x;
    int swz = (wg & 7) * (nwg >> 3) + (wg >> 3);
    int bx = swz % 16, by = swz / 16;
    int row0 = by * 128, col0 = bx * BN;
    int wrow = (w >> 1) * 64, wcol = (w & 1) * 32;
    f32x4 zero = {0.f, 0.f, 0.f, 0.f};
    f32x4 acc[4][NJ];
#pragma unroll
    for (int i = 0; i < 4; ++i)
#pragma unroll
        for (int j = 0; j < NJ; ++j) acc[i][j] = zero;
    uint4 a0[4], a1[4];
    float pl0[4], pl1[4];
    auto issueA = [&](int kt) {  // kt == head index (BK==DH)
#pragma unroll
        for (int p = 0; p < 4; ++p) {
            int u = tid + p * 256;
            int r = u >> 3, cu = u & 7;
            int scu = cu ^ (r & 7);
            size_t rrow = row0 + r;
            a0[p] = *(const uint4*)(po + rrow * DIM + kt * 64 + scu * 8);
            a1[p] = *(const uint4*)(po + (4096 + rrow) * DIM + kt * 64 + scu * 8);
            pl0[p] = pl[rrow * NHEADS + kt];
            pl1[p] = pl[(4096 + rrow) * NHEADS + kt];
        }
    };
    auto writeA = [&](int buf) {
#pragma unroll
        for (int p = 0; p < 4; ++p) {
            int u = tid + p * 256;
            float rl = 1.0f / (pl0[p] + pl1[p]);
            const unsigned short* e0 = (const unsigned short*)&a0[p];
            const unsigned short* e1 = (const unsigned short*)&a1[p];
            uint4 pk;
            unsigned int* pku = (unsigned int*)&pk;
#pragma unroll
            for (int j = 0; j < 4; ++j) {
                float lo = (bf2f(e0[2 * j]) + bf2f(e1[2 * j])) * rl;
                float hi = (bf2f(e0[2 * j + 1]) + bf2f(e1[2 * j + 1])) * rl;
                pku[j] = cvt_pk_bf16(lo, hi);
            }
            *(uint4*)(&As[buf][0] + u * 8) = pk;
        }
    };
    auto stageB = [&](int buf, int kt) {
#pragma unroll
        for (int p = 0; p < 2; ++p) {
            int ub = tid + p * 256;
            int r = ub >> 3, cu = ub & 7;
            int scu = cu ^ (r & 7);
            gld16(BT + (size_t)(col0 + r) * DIM + kt * 64 + scu * 8, &Bs[buf][0] + ub * 8);
        }
    };
    issueA(0);
    stageB(0, 0);
    asm volatile("s_waitcnt vmcnt(0)" ::: "memory");
    writeA(0);
    issueA(1);
    stageB(1, 1);
    asm volatile("s_waitcnt lgkmcnt(0)" ::: "memory");
    __builtin_amdgcn_s_barrier();
    __builtin_amdgcn_sched_barrier(0);
    for (int kt = 0; kt < nk; ++kt) {
        int cur = kt & 1;
        const unsigned short* Ab = &As[cur][0];
        const unsigned short* Bb = &Bs[cur][0];
        bf16x8 af[4][KK], bfr[NJ][KK];
#pragma unroll
        for (int i = 0; i < 4; ++i)
#pragma unroll
            for (int kk = 0; kk < KK; ++kk) {
                int rr = wrow + i * 16 + l15;
                int up = (kk * 4 + lhi) ^ (rr & 7);
                af[i][kk] = *(const bf16x8*)&Ab[rr * BK + up * 8];
            }
#pragma unroll
        for (int j = 0; j < NJ; ++j)
#pragma unroll
            for (int kk = 0; kk < KK; ++kk) {
                int rr = wcol + j * 16 + l15;
                int up = (kk * 4 + lhi) ^ (rr & 7);
                bfr[j][kk] = *(const bf16x8*)&Bb[rr * BK + up * 8];
            }
#pragma unroll
        for (int kk = 0; kk < KK; ++kk)
#pragma unroll
            for (int i = 0; i < 4; ++i)
#pragma unroll
                for (int j = 0; j < NJ; ++j)
                    acc[i][j] = __builtin_amdgcn_mfma_f32_16x16x32_bf16(af[i][kk], bfr[j][kk],
                                                                        acc[i][j], 0, 0, 0);
        __builtin_amdgcn_sched_barrier(0);
        if (kt + 1 < nk) {
            asm volatile("s_waitcnt vmcnt(0)" ::: "memory");  // A(kt+1) regs + B(kt+1) LDS landed
            writeA(cur ^ 1);
            asm volatile("s_waitcnt lgkmcnt(0)" ::: "memory");
            __builtin_amdgcn_s_barrier();  // all waves done reading cur; nxt fully built
            __builtin_amdgcn_sched_barrier(0);
            if (kt + 2 < nk) {
                issueA(kt + 2);
                stageB(cur, kt + 2);
            }
        }
    }
#pragma unroll
    for (int i = 0; i < 4; ++i)
#pragma unroll
        for (int j = 0; j < NJ; ++j)
#pragma unroll
            for (int r = 0; r < 4; ++r) {
                int row = row0 + wrow + i * 16 + lhi * 4 + r;
                int col = col0 + wcol + j * 16 + l15;
                float v = acc[i][j][r] + bias[col] + xres[(size_t)row * DIM + col];
                outb[(size_t)row * DIM + col] = f2bf(v);
            }
}

// ---------- flash attention, split-K=2 x q-reuse=2 (R8/R9 structure + setprio) ----------
__global__ __launch_bounds__(256) void attn_kernel(const unsigned short* __restrict__ qkv,
                                                   const unsigned short* __restrict__ vt,
                                                   unsigned short* __restrict__ po,
                                                   float* __restrict__ pl) {
    __shared__ unsigned short Ks[64 * 64];
    __shared__ unsigned short Vs[64 * 64];
    int tid = threadIdx.x;
    int lane = tid & 63, w = tid >> 6;
    int l15 = lane & 15, lhi = lane >> 4;
    int wg = blockIdx.x;  // 1024 blocks, 4/CU
    int swz = (wg & 7) * 128 + (wg >> 3);  // XCD-chunked
    int qt = swz & 15, half = (swz >> 4) & 1, h = (swz >> 5) & 15, b = swz >> 9;
    bf16x8 qf[2][2];
#pragma unroll
    for (int qg = 0; qg < 2; ++qg) {
        const unsigned short* qb =
            qkv + (size_t)(b * SEQ + qt * 128 + w * 32 + qg * 16 + l15) * 3072 + h * DH;
        qf[qg][0] = *(const bf16x8*)(qb + lhi * 8);
        qf[qg][1] = *(const bf16x8*)(qb + 32 + lhi * 8);
    }
    f32x4 zero = {0.f, 0.f, 0.f, 0.f};
    f32x4 oacc[2][4], lacc[2];
#pragma unroll
    for (int qg = 0; qg < 2; ++qg) {
        lacc[qg] = zero;
#pragma unroll
        for (int i = 0; i < 4; ++i) oacc[qg][i] = zero;
    }
    const short one_s = (short)0x3F80;  // bf16 1.0
    bf16x8 ones = {one_s, one_s, one_s, one_s, one_s, one_s, one_s, one_s};
    int srow = tid >> 3;
    int scx = (tid & 7) ^ (srow & 7);
    const unsigned short* kb = qkv + (size_t)b * SEQ * 3072 + 1024 + h * DH;
    const unsigned short* vb = vt + (size_t)(b * NHEADS + h) * DH * SEQ;
    const unsigned short* k0 = kb + (size_t)srow * 3072 + scx * 8;
    const unsigned short* v0 = vb + (size_t)srow * SEQ + scx * 8;
    auto stage = [&](int kg) {
        unsigned short* lk = &Ks[0] + tid * 8;
        unsigned short* lv = &Vs[0] + tid * 8;
        gld16(k0 + (size_t)kg * 64 * 3072, lk);
        gld16(k0 + ((size_t)kg * 64 + 32) * 3072, lk + 2048);
        gld16(v0 + kg * 64, lv);
        gld16(v0 + (size_t)32 * SEQ + kg * 64, lv + 2048);
    };
    int kx = l15 & 7;
    const int NT2 = SEQ / 64 / 2;  // 16 tiles per split
    for (int kt = 0; kt < NT2; ++kt) {
        stage(half * NT2 + kt);
        asm volatile("s_waitcnt vmcnt(0)" ::: "memory");
        __builtin_amdgcn_s_barrier();
        __builtin_amdgcn_sched_barrier(0);
        __builtin_amdgcn_s_setprio(1);
        f32x4 sacc[2][4];
#pragma unroll
        for (int nt = 0; nt < 4; ++nt) {
            bf16x8 kf0 = *(const bf16x8*)&Ks[(nt * 16 + l15) * 64 + ((lhi ^ kx) * 8)];
            bf16x8 kf1 = *(const bf16x8*)&Ks[(nt * 16 + l15) * 64 + (((4 + lhi) ^ kx) * 8)];
#pragma unroll
            for (int qg = 0; qg < 2; ++qg) {
                f32x4 z = __builtin_amdgcn_mfma_f32_16x16x32_bf16(kf0, qf[qg][0], zero, 0, 0, 0);
                sacc[qg][nt] = __builtin_amdgcn_mfma_f32_16x16x32_bf16(kf1, qf[qg][1], z, 0, 0, 0);
            }
        }
        bf16x8 pf[2][2];
#pragma unroll
        for (int qg = 0; qg < 2; ++qg)
#pragma unroll
            for (int kc = 0; kc < 2; ++kc) {
                union { bf16x8 v; unsigned int u[4]; } pu;
                pu.u[0] = cvt_pk_bf16(fexp2(sacc[qg][2 * kc][0]), fexp2(sacc[qg][2 * kc][1]));
                pu.u[1] = cvt_pk_bf16(fexp2(sacc[qg][2 * kc][2]), fexp2(sacc[qg][2 * kc][3]));
                pu.u[2] = cvt_pk_bf16(fexp2(sacc[qg][2 * kc + 1][0]), fexp2(sacc[qg][2 * kc + 1][1]));
                pu.u[3] = cvt_pk_bf16(fexp2(sacc[qg][2 * kc + 1][2]), fexp2(sacc[qg][2 * kc + 1][3]));
                pf[qg][kc] = pu.v;
            }
#pragma unroll
        for (int dt = 0; dt < 4; ++dt)
#pragma unroll
            for (int kc = 0; kc < 2; ++kc) {
                bf16x8 vf = *(const bf16x8*)&Vs[(dt * 16 + l15) * 64 + (((kc * 4 + lhi) ^ kx) * 8)];
#pragma unroll
                for (int qg = 0; qg < 2; ++qg)
                    oacc[qg][dt] =
                        __builtin_amdgcn_mfma_f32_16x16x32_bf16(vf, pf[qg][kc], oacc[qg][dt], 0, 0, 0);
            }
#pragma unroll
        for (int qg = 0; qg < 2; ++qg) {
            lacc[qg] = __builtin_amdgcn_mfma_f32_16x16x32_bf16(ones, pf[qg][0], lacc[qg], 0, 0, 0);
            lacc[qg] = __builtin_amdgcn_mfma_f32_16x16x32_bf16(ones, pf[qg][1], lacc[qg], 0, 0, 0);
        }
        __builtin_amdgcn_s_setprio(0);
        __builtin_amdgcn_sched_barrier(0);
        if (kt + 1 < NT2) {
            __builtin_amdgcn_s_barrier();  // all reads done before next stage overwrites
            __builtin_amdgcn_sched_barrier(0);
        }
    }
#pragma unroll
    for (int qg = 0; qg < 2; ++qg) {
        int rrow = b * SEQ + qt * 128 + w * 32 + qg * 16 + l15;
        unsigned short* pob = po + ((size_t)half * 4096 + rrow) * DIM + h * DH;
#pragma unroll
        for (int dt = 0; dt < 4; ++dt) {
            ushort4 st;
            st.x = f2bf(oacc[qg][dt][0]);
            st.y = f2bf(oacc[qg][dt][1]);
            st.z = f2bf(oacc[qg][dt][2]);
            st.w = f2bf(oacc[qg][dt][3]);
            *(ushort4*)(pob + dt * 16 + lhi * 4) = st;
        }
        if (lhi == 0) pl[((size_t)half * 4096 + rrow) * NHEADS + h] = lacc[qg][0];
    }
}

extern "C" void kernel_launch(void* const* d_in, const int* in_sizes, int n_in,
                              void* d_out, int out_size, void* d_ws, size_t ws_size,
                              hipStream_t stream) {
    (void)in_sizes; (void)n_in; (void)out_size; (void)ws_size;
    const float* x = (const float*)d_in[0];
    const float* w_qkv = (const float*)d_in[1];
    const float* w_out = (const float*)d_in[2];
    const float* b_out = (const float*)d_in[3];
    const float* g1 = (const float*)d_in[4];
    const float* bt1 = (const float*)d_in[5];
    const float* g2 = (const float*)d_in[6];
    const float* bt2 = (const float*)d_in[7];
    const float* w1 = (const float*)d_in[8];
    const float* b1 = (const float*)d_in[9];
    const float* w2 = (const float*)d_in[10];
    const float* b2 = (const float*)d_in[11];
    float* out = (float*)d_out;

    char* ws = (char*)d_ws;
    size_t off = 0;
    auto alloc = [&](size_t bytes) {
        void* p = ws + off;
        off += (bytes + 255) & ~(size_t)255;
        return p;
    };
    const int R = 2 * SEQ;  // 4096 rows
    unsigned short* xl    = (unsigned short*)alloc((size_t)R * DIM * 2);
    unsigned short* wqkvT = (unsigned short*)alloc((size_t)3 * DIM * DIM * 2);
    unsigned short* woutT = (unsigned short*)alloc((size_t)DIM * DIM * 2);
    unsigned short* w1T   = (unsigned short*)alloc((size_t)DIM * DIM * 2);
    unsigned short* w2T   = (unsigned short*)alloc((size_t)DIM * DIM * 2);
    unsigned short* qkvb  = (unsigned short*)alloc((size_t)R * 3 * DIM * 2);
    unsigned short* vtb   = (unsigned short*)alloc((size_t)R * DIM * 2);
    unsigned short* outb  = (unsigned short*)alloc((size_t)R * DIM * 2);  // residual stream (bf16)
    unsigned short* h2    = (unsigned short*)alloc((size_t)R * DIM * 2);
    unsigned short* ffn1  = (unsigned short*)alloc((size_t)R * DIM * 2);
    unsigned short* po = (unsigned short*)alloc((size_t)2 * R * DIM * 2);  // split-K partial O (bf16)
    float* pl = (float*)alloc((size_t)2 * R * NHEADS * 4);  // split-K partial l

    const float CS = 0.125f * 1.44269504f;  // attn scale * log2(e), folded into Q weights
    wtrans_ln<<<dim3(128, 32, 5), 256, 0, stream>>>(w_qkv, w_out, w1, w2, wqkvT, woutT, w1T, w2T,
                                                    CS, x, g1, bt1, xl);

    const unsigned int SH_QKV = (3 * 128 * 32 + 3 * 128 * 32) * 2;   // 48 KB (>= 128*130*2)
    const unsigned int SH_FFN = (3 * 128 * 64 + 3 * 64 * 64) * 2;    // 72 KB
    gemm_kernel<128, 32, 1, 0, 0, 0, 1>
        <<<dim3((3 * DIM / 128) * (R / 128)), 256, SH_QKV, stream>>>(
            xl, wqkvT, qkvb, nullptr, nullptr, vtb, R, 3 * DIM, DIM, 3 * DIM / 128);
    attn_kernel<<<2 * NHEADS * (SEQ / 128) * 2, 256, 0, stream>>>(qkvb, vtb, po, pl);
    gemm_oproj<<<dim3((DIM / 64) * (R / 128)), 256, 0, stream>>>(po, pl, woutT, outb, b_out, x);
    ln_bf16<<<R, 256, 0, stream>>>(outb, g2, bt2, h2);
    gemm_kernel<64, 64, 1, 1, 1, 0, 0><<<dim3((DIM / 64) * (R / 128)), 256, SH_FFN, stream>>>(
        h2, w1T, ffn1, b1, nullptr, nullptr, R, DIM, DIM, DIM / 64);
    gemm_kernel<64, 64, 0, 1, 0, 2, 0><<<dim3((DIM / 64) * (R / 128)), 256, SH_FFN, stream>>>(
        ffn1, w2T, out, b2, outb, nullptr, R, DIM, DIM, DIM / 64);
}

// Round 13
// 165.459 us; speedup vs baseline: 1.0678x; 1.0678x over previous
//
#include <hip/hip_runtime.h>
#include <math.h>

typedef __attribute__((ext_vector_type(4))) float f32x4;
typedef __attribute__((ext_vector_type(8))) short bf16x8;
typedef __attribute__((ext_vector_type(8))) unsigned short u16x8;

#define DIM 1024
#define SEQ 2048
#define NHEADS 16
#define DH 64

__device__ __forceinline__ unsigned short f2bf(float f) {
    unsigned int u = __builtin_bit_cast(unsigned int, f);
    u += 0x7fffu + ((u >> 16) & 1u);
    return (unsigned short)(u >> 16);
}

__device__ __forceinline__ float bf2f(unsigned short s) {
    unsigned int u = (unsigned int)s << 16;
    return __builtin_bit_cast(float, u);
}

__device__ __forceinline__ unsigned int cvt_pk_bf16(float lo, float hi) {
    unsigned int r;
    asm("v_cvt_pk_bf16_f32 %0, %1, %2" : "=v"(r) : "v"(lo), "v"(hi));
    return r;
}

__device__ __forceinline__ float fexp2(float x) {
    float r;
    asm("v_exp_f32 %0, %1" : "=v"(r) : "v"(x));
    return r;
}

__device__ __forceinline__ void gld16(const unsigned short* g, unsigned short* l) {
    __builtin_amdgcn_global_load_lds((const __attribute__((address_space(1))) void*)g,
                                     (__attribute__((address_space(3))) void*)l, 16, 0, 0);
}

// ---------- weight transposes (z=0..3) + LayerNorm1 (z=4) in one launch ----------
__global__ __launch_bounds__(256) void wtrans_ln(const float* __restrict__ wq,
                                                 const float* __restrict__ wo,
                                                 const float* __restrict__ wf1,
                                                 const float* __restrict__ wf2,
                                                 unsigned short* __restrict__ oq,
                                                 unsigned short* __restrict__ oo,
                                                 unsigned short* __restrict__ of1,
                                                 unsigned short* __restrict__ of2, float sc,
                                                 const float* __restrict__ x,
                                                 const float* __restrict__ g1,
                                                 const float* __restrict__ bt1,
                                                 unsigned short* __restrict__ xl) {
    int z = blockIdx.z;
    int bxi = blockIdx.x;
    int tid = threadIdx.x;
    if (z == 4) {  // LayerNorm over x rows
        int row = blockIdx.y * 128 + bxi;
        const float4* xr = (const float4*)(x + (size_t)row * DIM);
        float4 v = xr[tid];
        float s1 = v.x + v.y + v.z + v.w;
        float s2 = v.x * v.x + v.y * v.y + v.z * v.z + v.w * v.w;
#pragma unroll
        for (int m = 32; m >= 1; m >>= 1) {
            s1 += __shfl_xor(s1, m);
            s2 += __shfl_xor(s2, m);
        }
        __shared__ float r1[4], r2[4];
        int w = tid >> 6;
        if ((tid & 63) == 0) { r1[w] = s1; r2[w] = s2; }
        __syncthreads();
        s1 = r1[0] + r1[1] + r1[2] + r1[3];
        s2 = r2[0] + r2[1] + r2[2] + r2[3];
        float mu = s1 * (1.0f / DIM);
        float var = s2 * (1.0f / DIM) - mu * mu;
        float rstd = rsqrtf(var + 1e-5f);
        float4 g4 = ((const float4*)g1)[tid];
        float4 b4 = ((const float4*)bt1)[tid];
        ushort4 ov;
        ov.x = f2bf((v.x - mu) * rstd * g4.x + b4.x);
        ov.y = f2bf((v.y - mu) * rstd * g4.y + b4.y);
        ov.z = f2bf((v.z - mu) * rstd * g4.z + b4.z);
        ov.w = f2bf((v.w - mu) * rstd * g4.w + b4.w);
        *(ushort4*)(xl + (size_t)row * DIM + tid * 4) = ov;
        return;
    }
    if (bxi >= (z == 0 ? 96 : 32)) return;
    const float* w = z == 0 ? wq : z == 1 ? wo : z == 2 ? wf1 : wf2;
    unsigned short* wt = z == 0 ? oq : z == 1 ? oo : z == 2 ? of1 : of2;
    int N = z == 0 ? 3072 : 1024;
    int scale_n = z == 0 ? 1024 : 0;
    const int K = 1024;
    __shared__ float t[32][33];
    int n0 = bxi * 32, k0 = blockIdx.y * 32;
    int c = tid & 31, rb = tid >> 5;
#pragma unroll
    for (int i = 0; i < 4; ++i) {
        int r = rb + i * 8;
        t[r][c] = w[(size_t)(k0 + r) * N + n0 + c];
    }
    __syncthreads();
#pragma unroll
    for (int i = 0; i < 4; ++i) {
        int r = rb + i * 8;  // N-local
        float v = t[c][r];
        if (n0 + r < scale_n) v *= sc;
        wt[(size_t)(n0 + r) * K + k0 + c] = f2bf(v);
    }
}

// ---------- LayerNorm: bf16 in -> bf16 out ----------
__global__ __launch_bounds__(256) void ln_bf16(const unsigned short* __restrict__ x,
                                               const float* __restrict__ g,
                                               const float* __restrict__ bt,
                                               unsigned short* __restrict__ o) {
    int row = blockIdx.x, tid = threadIdx.x;
    ushort4 v4 = *(const ushort4*)(x + (size_t)row * DIM + tid * 4);
    float vx = bf2f(v4.x), vy = bf2f(v4.y), vz = bf2f(v4.z), vw = bf2f(v4.w);
    float s1 = vx + vy + vz + vw;
    float s2 = vx * vx + vy * vy + vz * vz + vw * vw;
#pragma unroll
    for (int m = 32; m >= 1; m >>= 1) {
        s1 += __shfl_xor(s1, m);
        s2 += __shfl_xor(s2, m);
    }
    __shared__ float r1[4], r2[4];
    int w = tid >> 6;
    if ((tid & 63) == 0) { r1[w] = s1; r2[w] = s2; }
    __syncthreads();
    s1 = r1[0] + r1[1] + r1[2] + r1[3];
    s2 = r2[0] + r2[1] + r2[2] + r2[3];
    float mu = s1 * (1.0f / DIM);
    float var = s2 * (1.0f / DIM) - mu * mu;
    float rstd = rsqrtf(var + 1e-5f);
    float4 g4 = ((const float4*)g)[tid];
    float4 b4 = ((const float4*)bt)[tid];
    ushort4 ov;
    ov.x = f2bf((vx - mu) * rstd * g4.x + b4.x);
    ov.y = f2bf((vy - mu) * rstd * g4.y + b4.y);
    ov.z = f2bf((vz - mu) * rstd * g4.z + b4.z);
    ov.w = f2bf((vw - mu) * rstd * g4.w + b4.w);
    *(ushort4*)(o + (size_t)row * DIM + tid * 4) = ov;
}

// ---------- GEMM, 3-buffer counted-vmcnt pipeline, XOR-swizzled LDS ----------
// C[M,N] = A[M,K](bf16) @ BT[N,K](bf16)^T. BM=128.
// VT=1: blocks with col0>=2048 write sigma-permuted transposed V to vt instead of C.
// RESID: 0=none, 1=f32 resid, 2=bf16 resid.
template <int BN, int BK, int OBF, int BIAS, int GELU_, int RESID, int VT>
__global__ __launch_bounds__(256) void gemm_kernel(const unsigned short* __restrict__ A,
                                                   const unsigned short* __restrict__ BT,
                                                   void* __restrict__ C,
                                                   const float* __restrict__ bias,
                                                   const void* __restrict__ resid,
                                                   unsigned short* __restrict__ vt,
                                                   int M, int N, int K, int nbx) {
    constexpr int U = BK / 8;              // 16B units per row
    constexpr int NAU = 128 * U;           // A-tile units
    constexpr int NBU = BN * U;            // B-tile units
    constexpr int PT = (NAU + NBU) / 256;  // gld16 per thread per stage
    constexpr int NJ = BN / 32;
    constexpr int KK = BK / 32;
    extern __shared__ char smem[];
    unsigned short* As = (unsigned short*)smem;      // [3][128*BK]
    unsigned short* Bs = As + 3 * 128 * BK;          // [3][BN*BK]
    int tid = threadIdx.x;
    int lane = tid & 63, w = tid >> 6;
    int l15 = lane & 15, lhi = lane >> 4;
    int nwg = gridDim.x, wg = blockIdx.x;
    int swz = (wg & 7) * (nwg >> 3) + (wg >> 3);  // XCD-chunked (nwg % 8 == 0)
    int bx = swz % nbx, by = swz / nbx;
    int row0 = by * 128, col0 = bx * BN;
    int wrow = (w >> 1) * 64, wcol = (w & 1) * (16 * NJ);
    f32x4 zero = {0.f, 0.f, 0.f, 0.f};
    f32x4 acc[4][NJ];
#pragma unroll
    for (int i = 0; i < 4; ++i)
#pragma unroll
        for (int j = 0; j < NJ; ++j) acc[i][j] = zero;
    auto stage = [&](int buf, int kt) {
#pragma unroll
        for (int p = 0; p < PT; ++p) {
            if (p * 256 < NAU) {
                int u = tid + p * 256;
                int r = u / U, cu = u % U;
                int scu = cu ^ (r & (U - 1));
                gld16(A + (size_t)(row0 + r) * K + kt * BK + scu * 8, As + buf * 128 * BK + u * 8);
            } else {
                int ub = tid + p * 256 - NAU;
                int r = ub / U, cu = ub % U;
                int scu = cu ^ (r & (U - 1));
                gld16(BT + (size_t)(col0 + r) * K + kt * BK + scu * 8, Bs + buf * BN * BK + ub * 8);
            }
        }
    };
    int nk = K / BK;
    stage(0, 0);
    stage(1, 1);
    asm volatile("s_waitcnt vmcnt(%0)" ::"i"(PT) : "memory");
    __builtin_amdgcn_s_barrier();
    __builtin_amdgcn_sched_barrier(0);
    int cur = 0;
    for (int kt = 0; kt < nk; ++kt) {
        int nxt2 = cur + 2 >= 3 ? cur - 1 : cur + 2;
        if (kt + 2 < nk) stage(nxt2, kt + 2);
        const unsigned short* Ab = As + cur * 128 * BK;
        const unsigned short* Bb = Bs + cur * BN * BK;
        bf16x8 af[4][KK], bfr[NJ][KK];
#pragma unroll
        for (int i = 0; i < 4; ++i)
#pragma unroll
            for (int kk = 0; kk < KK; ++kk) {
                int rr = wrow + i * 16 + l15;
                int up = (kk * 4 + lhi) ^ (rr & (U - 1));
                af[i][kk] = *(const bf16x8*)&Ab[rr * BK + up * 8];
            }
#pragma unroll
        for (int j = 0; j < NJ; ++j)
#pragma unroll
            for (int kk = 0; kk < KK; ++kk) {
                int rr = wcol + j * 16 + l15;
                int up = (kk * 4 + lhi) ^ (rr & (U - 1));
                bfr[j][kk] = *(const bf16x8*)&Bb[rr * BK + up * 8];
            }
#pragma unroll
        for (int kk = 0; kk < KK; ++kk)
#pragma unroll
            for (int i = 0; i < 4; ++i)
#pragma unroll
                for (int j = 0; j < NJ; ++j)
                    acc[i][j] = __builtin_amdgcn_mfma_f32_16x16x32_bf16(af[i][kk], bfr[j][kk],
                                                                        acc[i][j], 0, 0, 0);
        __builtin_amdgcn_sched_barrier(0);
        if (kt + 1 < nk) {
            if (kt + 2 < nk)
                asm volatile("s_waitcnt vmcnt(%0)" ::"i"(PT) : "memory");
            else
                asm volatile("s_waitcnt vmcnt(0)" ::: "memory");
            __builtin_amdgcn_s_barrier();
            __builtin_amdgcn_sched_barrier(0);
        }
        cur = cur + 1 == 3 ? 0 : cur + 1;
    }
    if (VT && col0 >= 2048) {
        // V block: transpose + sigma-permute into vt[b,h][d][n]; skip normal C write.
        __syncthreads();  // all waves done with staging LDS
        unsigned short* Ct = (unsigned short*)smem;  // [128][130] bf16 (33280 B)
#pragma unroll
        for (int i = 0; i < 4; ++i)
#pragma unroll
            for (int j = 0; j < NJ; ++j)
#pragma unroll
                for (int r = 0; r < 4; ++r)
                    Ct[(wrow + i * 16 + lhi * 4 + r) * 130 + (wcol + j * 16 + l15)] =
                        f2bf(acc[i][j][r]);
        __syncthreads();
        int l = tid & 63, wv = tid >> 6;
        int sig = (l & 32) | ((l & 4) << 2) | ((l & 24) >> 1) | (l & 3);
        int b = row0 >> 11, n0 = row0 & 2047;
        int h0 = (col0 - 2048) >> 6;
        for (int c = wv * 64; c < wv * 64 + 64; ++c) {
            int ntl = c & 1, hl = (c >> 1) & 1, d = c >> 2;
            unsigned short v = Ct[(ntl * 64 + sig) * 130 + hl * 64 + d];
            vt[((size_t)(b * NHEADS + h0 + hl) * DH + d) * SEQ + n0 + ntl * 64 + l] = v;
        }
        return;
    }
#pragma unroll
    for (int i = 0; i < 4; ++i)
#pragma unroll
        for (int j = 0; j < NJ; ++j)
#pragma unroll
            for (int r = 0; r < 4; ++r) {
                int row = row0 + wrow + i * 16 + lhi * 4 + r;
                int col = col0 + wcol + j * 16 + l15;
                float v = acc[i][j][r];
                if (BIAS) v += bias[col];
                if (GELU_) v = 0.5f * v * (1.0f + erff(v * 0.70710678118f));
                if (RESID == 1) v += ((const float*)resid)[(size_t)row * N + col];
                if (RESID == 2) v += bf2f(((const unsigned short*)resid)[(size_t)row * N + col]);
                if (OBF)
                    ((unsigned short*)C)[(size_t)row * N + col] = f2bf(v);
                else
                    ((float*)C)[(size_t)row * N + col] = v;
            }
}

// ---------- flash attention, split-K=2 x q-reuse=2: bf16 partial O + f32 partial l ----------
__global__ __launch_bounds__(256) void attn_kernel(const unsigned short* __restrict__ qkv,
                                                   const unsigned short* __restrict__ vt,
                                                   unsigned short* __restrict__ po,
                                                   float* __restrict__ pl) {
    __shared__ unsigned short Ks[64 * 64];
    __shared__ unsigned short Vs[64 * 64];
    int tid = threadIdx.x;
    int lane = tid & 63, w = tid >> 6;
    int l15 = lane & 15, lhi = lane >> 4;
    int wg = blockIdx.x;  // 1024 blocks, 4/CU
    int swz = (wg & 7) * 128 + (wg >> 3);  // XCD-chunked
    int qt = swz & 15, half = (swz >> 4) & 1, h = (swz >> 5) & 15, b = swz >> 9;
    // wave w owns q rows [qt*128 + w*32 + qg*16, +16); Q pre-scaled by 0.125*log2e
    bf16x8 qf[2][2];
#pragma unroll
    for (int qg = 0; qg < 2; ++qg) {
        const unsigned short* qb =
            qkv + (size_t)(b * SEQ + qt * 128 + w * 32 + qg * 16 + l15) * 3072 + h * DH;
        qf[qg][0] = *(const bf16x8*)(qb + lhi * 8);
        qf[qg][1] = *(const bf16x8*)(qb + 32 + lhi * 8);
    }
    f32x4 zero = {0.f, 0.f, 0.f, 0.f};
    f32x4 oacc[2][4], lacc[2];
#pragma unroll
    for (int qg = 0; qg < 2; ++qg) {
        lacc[qg] = zero;
#pragma unroll
        for (int i = 0; i < 4; ++i) oacc[qg][i] = zero;
    }
    const short one_s = (short)0x3F80;  // bf16 1.0
    bf16x8 ones = {one_s, one_s, one_s, one_s, one_s, one_s, one_s, one_s};
    // staging: dest linear, source 16B-unit XOR-swizzled with row&7
    int srow = tid >> 3;
    int scx = (tid & 7) ^ (srow & 7);
    const unsigned short* kb = qkv + (size_t)b * SEQ * 3072 + 1024 + h * DH;
    const unsigned short* vb = vt + (size_t)(b * NHEADS + h) * DH * SEQ;
    const unsigned short* k0 = kb + (size_t)srow * 3072 + scx * 8;
    const unsigned short* v0 = vb + (size_t)srow * SEQ + scx * 8;
    auto stage = [&](int kg) {
        unsigned short* lk = &Ks[0] + tid * 8;
        unsigned short* lv = &Vs[0] + tid * 8;
        gld16(k0 + (size_t)kg * 64 * 3072, lk);
        gld16(k0 + ((size_t)kg * 64 + 32) * 3072, lk + 2048);
        gld16(v0 + kg * 64, lv);
        gld16(v0 + (size_t)32 * SEQ + kg * 64, lv + 2048);
    };
    int kx = l15 & 7;
    const int NT2 = SEQ / 64 / 2;  // 16 tiles per split
    for (int kt = 0; kt < NT2; ++kt) {
        stage(half * NT2 + kt);
        asm volatile("s_waitcnt vmcnt(0)" ::: "memory");
        __builtin_amdgcn_s_barrier();
        __builtin_amdgcn_sched_barrier(0);
        // S^T = K @ Q^T : lane holds S[kv=16nt+4lhi+r][q=l15] (per qg)
        f32x4 sacc[2][4];
#pragma unroll
        for (int nt = 0; nt < 4; ++nt) {
            bf16x8 kf0 = *(const bf16x8*)&Ks[(nt * 16 + l15) * 64 + ((lhi ^ kx) * 8)];
            bf16x8 kf1 = *(const bf16x8*)&Ks[(nt * 16 + l15) * 64 + (((4 + lhi) ^ kx) * 8)];
#pragma unroll
            for (int qg = 0; qg < 2; ++qg) {
                f32x4 z = __builtin_amdgcn_mfma_f32_16x16x32_bf16(kf0, qf[qg][0], zero, 0, 0, 0);
                sacc[qg][nt] = __builtin_amdgcn_mfma_f32_16x16x32_bf16(kf1, qf[qg][1], z, 0, 0, 0);
            }
        }
        // P = exp2(S) (scale pre-folded into Q), packed lane-local via sigma-permuted V
        bf16x8 pf[2][2];
#pragma unroll
        for (int qg = 0; qg < 2; ++qg)
#pragma unroll
            for (int kc = 0; kc < 2; ++kc) {
                union { bf16x8 v; unsigned int u[4]; } pu;
                pu.u[0] = cvt_pk_bf16(fexp2(sacc[qg][2 * kc][0]), fexp2(sacc[qg][2 * kc][1]));
                pu.u[1] = cvt_pk_bf16(fexp2(sacc[qg][2 * kc][2]), fexp2(sacc[qg][2 * kc][3]));
                pu.u[2] = cvt_pk_bf16(fexp2(sacc[qg][2 * kc + 1][0]), fexp2(sacc[qg][2 * kc + 1][1]));
                pu.u[3] = cvt_pk_bf16(fexp2(sacc[qg][2 * kc + 1][2]), fexp2(sacc[qg][2 * kc + 1][3]));
                pf[qg][kc] = pu.v;
            }
        // O^T += V^T @ P^T ; l += ones @ P^T  (V-frags shared across qg)
#pragma unroll
        for (int dt = 0; dt < 4; ++dt)
#pragma unroll
            for (int kc = 0; kc < 2; ++kc) {
                bf16x8 vf = *(const bf16x8*)&Vs[(dt * 16 + l15) * 64 + (((kc * 4 + lhi) ^ kx) * 8)];
#pragma unroll
                for (int qg = 0; qg < 2; ++qg)
                    oacc[qg][dt] =
                        __builtin_amdgcn_mfma_f32_16x16x32_bf16(vf, pf[qg][kc], oacc[qg][dt], 0, 0, 0);
            }
#pragma unroll
        for (int qg = 0; qg < 2; ++qg) {
            lacc[qg] = __builtin_amdgcn_mfma_f32_16x16x32_bf16(ones, pf[qg][0], lacc[qg], 0, 0, 0);
            lacc[qg] = __builtin_amdgcn_mfma_f32_16x16x32_bf16(ones, pf[qg][1], lacc[qg], 0, 0, 0);
        }
        __builtin_amdgcn_sched_barrier(0);
        if (kt + 1 < NT2) {
            __builtin_amdgcn_s_barrier();  // all reads done before next stage overwrites
            __builtin_amdgcn_sched_barrier(0);
        }
    }
#pragma unroll
    for (int qg = 0; qg < 2; ++qg) {
        int rrow = b * SEQ + qt * 128 + w * 32 + qg * 16 + l15;
        unsigned short* pob = po + ((size_t)half * 4096 + rrow) * DIM + h * DH;
#pragma unroll
        for (int dt = 0; dt < 4; ++dt) {
            ushort4 st;
            st.x = f2bf(oacc[qg][dt][0]);
            st.y = f2bf(oacc[qg][dt][1]);
            st.z = f2bf(oacc[qg][dt][2]);
            st.w = f2bf(oacc[qg][dt][3]);
            *(ushort4*)(pob + dt * 16 + lhi * 4) = st;
        }
        if (lhi == 0) pl[((size_t)half * 4096 + rrow) * NHEADS + h] = lacc[qg][0];
    }
}

// ---------- split-K combine: O = (O0+O1)/(l0+l1), bf16 partials -> bf16 ----------
__global__ __launch_bounds__(256) void attn_combine(const unsigned short* __restrict__ po,
                                                    const float* __restrict__ pl,
                                                    unsigned short* __restrict__ o) {
    int r = blockIdx.x, tid = threadIdx.x;
    int d0 = tid * 4, h = d0 >> 6;
    ushort4 a = *(const ushort4*)(po + (size_t)r * DIM + d0);
    ushort4 c = *(const ushort4*)(po + (size_t)(4096 + r) * DIM + d0);
    float rl = 1.0f / (pl[(size_t)r * NHEADS + h] + pl[(size_t)(4096 + r) * NHEADS + h]);
    ushort4 ov;
    ov.x = f2bf((bf2f(a.x) + bf2f(c.x)) * rl);
    ov.y = f2bf((bf2f(a.y) + bf2f(c.y)) * rl);
    ov.z = f2bf((bf2f(a.z) + bf2f(c.z)) * rl);
    ov.w = f2bf((bf2f(a.w) + bf2f(c.w)) * rl);
    *(ushort4*)(o + (size_t)r * DIM + d0) = ov;
}

extern "C" void kernel_launch(void* const* d_in, const int* in_sizes, int n_in,
                              void* d_out, int out_size, void* d_ws, size_t ws_size,
                              hipStream_t stream) {
    (void)in_sizes; (void)n_in; (void)out_size; (void)ws_size;
    const float* x = (const float*)d_in[0];
    const float* w_qkv = (const float*)d_in[1];
    const float* w_out = (const float*)d_in[2];
    const float* b_out = (const float*)d_in[3];
    const float* g1 = (const float*)d_in[4];
    const float* bt1 = (const float*)d_in[5];
    const float* g2 = (const float*)d_in[6];
    const float* bt2 = (const float*)d_in[7];
    const float* w1 = (const float*)d_in[8];
    const float* b1 = (const float*)d_in[9];
    const float* w2 = (const float*)d_in[10];
    const float* b2 = (const float*)d_in[11];
    float* out = (float*)d_out;

    char* ws = (char*)d_ws;
    size_t off = 0;
    auto alloc = [&](size_t bytes) {
        void* p = ws + off;
        off += (bytes + 255) & ~(size_t)255;
        return p;
    };
    const int R = 2 * SEQ;  // 4096 rows
    unsigned short* xl    = (unsigned short*)alloc((size_t)R * DIM * 2);
    unsigned short* wqkvT = (unsigned short*)alloc((size_t)3 * DIM * DIM * 2);
    unsigned short* woutT = (unsigned short*)alloc((size_t)DIM * DIM * 2);
    unsigned short* w1T   = (unsigned short*)alloc((size_t)DIM * DIM * 2);
    unsigned short* w2T   = (unsigned short*)alloc((size_t)DIM * DIM * 2);
    unsigned short* qkvb  = (unsigned short*)alloc((size_t)R * 3 * DIM * 2);
    unsigned short* vtb   = (unsigned short*)alloc((size_t)R * DIM * 2);
    unsigned short* attO  = (unsigned short*)alloc((size_t)R * DIM * 2);
    unsigned short* outb  = (unsigned short*)alloc((size_t)R * DIM * 2);  // residual stream (bf16)
    unsigned short* h2    = (unsigned short*)alloc((size_t)R * DIM * 2);
    unsigned short* ffn1  = (unsigned short*)alloc((size_t)R * DIM * 2);
    unsigned short* po = (unsigned short*)alloc((size_t)2 * R * DIM * 2);  // split-K partial O (bf16)
    float* pl = (float*)alloc((size_t)2 * R * NHEADS * 4);  // split-K partial l

    const float CS = 0.125f * 1.44269504f;  // attn scale * log2(e), folded into Q weights
    wtrans_ln<<<dim3(128, 32, 5), 256, 0, stream>>>(w_qkv, w_out, w1, w2, wqkvT, woutT, w1T, w2T,
                                                    CS, x, g1, bt1, xl);

    const unsigned int SH_QKV = (3 * 128 * 32 + 3 * 128 * 32) * 2;   // 48 KB (>= 128*130*2)
    const unsigned int SH_FFN = (3 * 128 * 64 + 3 * 64 * 64) * 2;    // 72 KB
    gemm_kernel<128, 32, 1, 0, 0, 0, 1>
        <<<dim3((3 * DIM / 128) * (R / 128)), 256, SH_QKV, stream>>>(
            xl, wqkvT, qkvb, nullptr, nullptr, vtb, R, 3 * DIM, DIM, 3 * DIM / 128);
    attn_kernel<<<2 * NHEADS * (SEQ / 128) * 2, 256, 0, stream>>>(qkvb, vtb, po, pl);
    attn_combine<<<R, 256, 0, stream>>>(po, pl, attO);
    gemm_kernel<64, 64, 1, 1, 0, 1, 0><<<dim3((DIM / 64) * (R / 128)), 256, SH_FFN, stream>>>(
        attO, woutT, outb, b_out, x, nullptr, R, DIM, DIM, DIM / 64);
    ln_bf16<<<R, 256, 0, stream>>>(outb, g2, bt2, h2);
    gemm_kernel<64, 64, 1, 1, 1, 0, 0><<<dim3((DIM / 64) * (R / 128)), 256, SH_FFN, stream>>>(
        h2, w1T, ffn1, b1, nullptr, nullptr, R, DIM, DIM, DIM / 64);
    gemm_kernel<64, 64, 0, 1, 0, 2, 0><<<dim3((DIM / 64) * (R / 128)), 256, SH_FFN, stream>>>(
        ffn1, w2T, out, b2, outb, nullptr, R, DIM, DIM, DIM / 64);
}

// Round 14
// 160.335 us; speedup vs baseline: 1.1019x; 1.0320x over previous
//
#include <hip/hip_runtime.h>
#include <math.h>

typedef __attribute__((ext_vector_type(4))) float f32x4;
typedef __attribute__((ext_vector_type(8))) short bf16x8;
typedef __attribute__((ext_vector_type(8))) unsigned short u16x8;

#define DIM 1024
#define SEQ 2048
#define NHEADS 16
#define DH 64

__device__ __forceinline__ unsigned short f2bf(float f) {
    unsigned int u = __builtin_bit_cast(unsigned int, f);
    u += 0x7fffu + ((u >> 16) & 1u);
    return (unsigned short)(u >> 16);
}

__device__ __forceinline__ float bf2f(unsigned short s) {
    unsigned int u = (unsigned int)s << 16;
    return __builtin_bit_cast(float, u);
}

__device__ __forceinline__ unsigned int cvt_pk_bf16(float lo, float hi) {
    unsigned int r;
    asm("v_cvt_pk_bf16_f32 %0, %1, %2" : "=v"(r) : "v"(lo), "v"(hi));
    return r;
}

__device__ __forceinline__ float fexp2(float x) {
    float r;
    asm("v_exp_f32 %0, %1" : "=v"(r) : "v"(x));
    return r;
}

__device__ __forceinline__ void gld16(const unsigned short* g, unsigned short* l) {
    __builtin_amdgcn_global_load_lds((const __attribute__((address_space(1))) void*)g,
                                     (__attribute__((address_space(3))) void*)l, 16, 0, 0);
}

// ---------- weight transposes (z=0..3) + LayerNorm1 (z=4) in one launch ----------
__global__ __launch_bounds__(256) void wtrans_ln(const float* __restrict__ wq,
                                                 const float* __restrict__ wo,
                                                 const float* __restrict__ wf1,
                                                 const float* __restrict__ wf2,
                                                 unsigned short* __restrict__ oq,
                                                 unsigned short* __restrict__ oo,
                                                 unsigned short* __restrict__ of1,
                                                 unsigned short* __restrict__ of2, float sc,
                                                 const float* __restrict__ x,
                                                 const float* __restrict__ g1,
                                                 const float* __restrict__ bt1,
                                                 unsigned short* __restrict__ xl) {
    int z = blockIdx.z;
    int bxi = blockIdx.x;
    int tid = threadIdx.x;
    if (z == 4) {  // LayerNorm over x rows
        int row = blockIdx.y * 128 + bxi;
        const float4* xr = (const float4*)(x + (size_t)row * DIM);
        float4 v = xr[tid];
        float s1 = v.x + v.y + v.z + v.w;
        float s2 = v.x * v.x + v.y * v.y + v.z * v.z + v.w * v.w;
#pragma unroll
        for (int m = 32; m >= 1; m >>= 1) {
            s1 += __shfl_xor(s1, m);
            s2 += __shfl_xor(s2, m);
        }
        __shared__ float r1[4], r2[4];
        int w = tid >> 6;
        if ((tid & 63) == 0) { r1[w] = s1; r2[w] = s2; }
        __syncthreads();
        s1 = r1[0] + r1[1] + r1[2] + r1[3];
        s2 = r2[0] + r2[1] + r2[2] + r2[3];
        float mu = s1 * (1.0f / DIM);
        float var = s2 * (1.0f / DIM) - mu * mu;
        float rstd = rsqrtf(var + 1e-5f);
        float4 g4 = ((const float4*)g1)[tid];
        float4 b4 = ((const float4*)bt1)[tid];
        ushort4 ov;
        ov.x = f2bf((v.x - mu) * rstd * g4.x + b4.x);
        ov.y = f2bf((v.y - mu) * rstd * g4.y + b4.y);
        ov.z = f2bf((v.z - mu) * rstd * g4.z + b4.z);
        ov.w = f2bf((v.w - mu) * rstd * g4.w + b4.w);
        *(ushort4*)(xl + (size_t)row * DIM + tid * 4) = ov;
        return;
    }
    if (bxi >= (z == 0 ? 96 : 32)) return;
    const float* w = z == 0 ? wq : z == 1 ? wo : z == 2 ? wf1 : wf2;
    unsigned short* wt = z == 0 ? oq : z == 1 ? oo : z == 2 ? of1 : of2;
    int N = z == 0 ? 3072 : 1024;
    int scale_n = z == 0 ? 1024 : 0;
    const int K = 1024;
    __shared__ float t[32][33];
    int n0 = bxi * 32, k0 = blockIdx.y * 32;
    int c = tid & 31, rb = tid >> 5;
#pragma unroll
    for (int i = 0; i < 4; ++i) {
        int r = rb + i * 8;
        t[r][c] = w[(size_t)(k0 + r) * N + n0 + c];
    }
    __syncthreads();
#pragma unroll
    for (int i = 0; i < 4; ++i) {
        int r = rb + i * 8;  // N-local
        float v = t[c][r];
        if (n0 + r < scale_n) v *= sc;
        wt[(size_t)(n0 + r) * K + k0 + c] = f2bf(v);
    }
}

// ---------- LayerNorm: bf16 in -> bf16 out ----------
__global__ __launch_bounds__(256) void ln_bf16(const unsigned short* __restrict__ x,
                                               const float* __restrict__ g,
                                               const float* __restrict__ bt,
                                               unsigned short* __restrict__ o) {
    int row = blockIdx.x, tid = threadIdx.x;
    ushort4 v4 = *(const ushort4*)(x + (size_t)row * DIM + tid * 4);
    float vx = bf2f(v4.x), vy = bf2f(v4.y), vz = bf2f(v4.z), vw = bf2f(v4.w);
    float s1 = vx + vy + vz + vw;
    float s2 = vx * vx + vy * vy + vz * vz + vw * vw;
#pragma unroll
    for (int m = 32; m >= 1; m >>= 1) {
        s1 += __shfl_xor(s1, m);
        s2 += __shfl_xor(s2, m);
    }
    __shared__ float r1[4], r2[4];
    int w = tid >> 6;
    if ((tid & 63) == 0) { r1[w] = s1; r2[w] = s2; }
    __syncthreads();
    s1 = r1[0] + r1[1] + r1[2] + r1[3];
    s2 = r2[0] + r2[1] + r2[2] + r2[3];
    float mu = s1 * (1.0f / DIM);
    float var = s2 * (1.0f / DIM) - mu * mu;
    float rstd = rsqrtf(var + 1e-5f);
    float4 g4 = ((const float4*)g)[tid];
    float4 b4 = ((const float4*)bt)[tid];
    ushort4 ov;
    ov.x = f2bf((vx - mu) * rstd * g4.x + b4.x);
    ov.y = f2bf((vy - mu) * rstd * g4.y + b4.y);
    ov.z = f2bf((vz - mu) * rstd * g4.z + b4.z);
    ov.w = f2bf((vw - mu) * rstd * g4.w + b4.w);
    *(ushort4*)(o + (size_t)row * DIM + tid * 4) = ov;
}

// ---------- GEMM, 3-buffer counted-vmcnt pipeline, XOR-swizzled LDS ----------
// C[M,N] = A[M,K](bf16) @ BT[N,K](bf16)^T. BM=128.
// VT=1: blocks with col0>=2048 write sigma-permuted transposed V to vt instead of C.
// RESID: 0=none, 1=f32 resid, 2=bf16 resid.
template <int BN, int BK, int OBF, int BIAS, int GELU_, int RESID, int VT>
__global__ __launch_bounds__(256) void gemm_kernel(const unsigned short* __restrict__ A,
                                                   const unsigned short* __restrict__ BT,
                                                   void* __restrict__ C,
                                                   const float* __restrict__ bias,
                                                   const void* __restrict__ resid,
                                                   unsigned short* __restrict__ vt,
                                                   int M, int N, int K, int nbx) {
    constexpr int U = BK / 8;              // 16B units per row
    constexpr int NAU = 128 * U;           // A-tile units
    constexpr int NBU = BN * U;            // B-tile units
    constexpr int PT = (NAU + NBU) / 256;  // gld16 per thread per stage
    constexpr int NJ = BN / 32;
    constexpr int KK = BK / 32;
    extern __shared__ char smem[];
    unsigned short* As = (unsigned short*)smem;      // [3][128*BK]
    unsigned short* Bs = As + 3 * 128 * BK;          // [3][BN*BK]
    int tid = threadIdx.x;
    int lane = tid & 63, w = tid >> 6;
    int l15 = lane & 15, lhi = lane >> 4;
    int nwg = gridDim.x, wg = blockIdx.x;
    int swz = (wg & 7) * (nwg >> 3) + (wg >> 3);  // XCD-chunked (nwg % 8 == 0)
    int bx = swz % nbx, by = swz / nbx;
    int row0 = by * 128, col0 = bx * BN;
    int wrow = (w >> 1) * 64, wcol = (w & 1) * (16 * NJ);
    f32x4 zero = {0.f, 0.f, 0.f, 0.f};
    f32x4 acc[4][NJ];
#pragma unroll
    for (int i = 0; i < 4; ++i)
#pragma unroll
        for (int j = 0; j < NJ; ++j) acc[i][j] = zero;
    auto stage = [&](int buf, int kt) {
#pragma unroll
        for (int p = 0; p < PT; ++p) {
            if (p * 256 < NAU) {
                int u = tid + p * 256;
                int r = u / U, cu = u % U;
                int scu = cu ^ (r & (U - 1));
                gld16(A + (size_t)(row0 + r) * K + kt * BK + scu * 8, As + buf * 128 * BK + u * 8);
            } else {
                int ub = tid + p * 256 - NAU;
                int r = ub / U, cu = ub % U;
                int scu = cu ^ (r & (U - 1));
                gld16(BT + (size_t)(col0 + r) * K + kt * BK + scu * 8, Bs + buf * BN * BK + ub * 8);
            }
        }
    };
    int nk = K / BK;
    stage(0, 0);
    stage(1, 1);
    asm volatile("s_waitcnt vmcnt(%0)" ::"i"(PT) : "memory");
    __builtin_amdgcn_s_barrier();
    __builtin_amdgcn_sched_barrier(0);
    int cur = 0;
    for (int kt = 0; kt < nk; ++kt) {
        int nxt2 = cur + 2 >= 3 ? cur - 1 : cur + 2;
        if (kt + 2 < nk) stage(nxt2, kt + 2);
        const unsigned short* Ab = As + cur * 128 * BK;
        const unsigned short* Bb = Bs + cur * BN * BK;
        bf16x8 af[4][KK], bfr[NJ][KK];
#pragma unroll
        for (int i = 0; i < 4; ++i)
#pragma unroll
            for (int kk = 0; kk < KK; ++kk) {
                int rr = wrow + i * 16 + l15;
                int up = (kk * 4 + lhi) ^ (rr & (U - 1));
                af[i][kk] = *(const bf16x8*)&Ab[rr * BK + up * 8];
            }
#pragma unroll
        for (int j = 0; j < NJ; ++j)
#pragma unroll
            for (int kk = 0; kk < KK; ++kk) {
                int rr = wcol + j * 16 + l15;
                int up = (kk * 4 + lhi) ^ (rr & (U - 1));
                bfr[j][kk] = *(const bf16x8*)&Bb[rr * BK + up * 8];
            }
#pragma unroll
        for (int kk = 0; kk < KK; ++kk)
#pragma unroll
            for (int i = 0; i < 4; ++i)
#pragma unroll
                for (int j = 0; j < NJ; ++j)
                    acc[i][j] = __builtin_amdgcn_mfma_f32_16x16x32_bf16(af[i][kk], bfr[j][kk],
                                                                        acc[i][j], 0, 0, 0);
        __builtin_amdgcn_sched_barrier(0);
        if (kt + 1 < nk) {
            if (kt + 2 < nk)
                asm volatile("s_waitcnt vmcnt(%0)" ::"i"(PT) : "memory");
            else
                asm volatile("s_waitcnt vmcnt(0)" ::: "memory");
            __builtin_amdgcn_s_barrier();
            __builtin_amdgcn_sched_barrier(0);
        }
        cur = cur + 1 == 3 ? 0 : cur + 1;
    }
    if (VT && col0 >= 2048) {
        // V block: transpose + sigma-permute into vt[b,h][d][n]; skip normal C write.
        __syncthreads();  // all waves done with staging LDS
        unsigned short* Ct = (unsigned short*)smem;  // [128][130] bf16 (33280 B)
#pragma unroll
        for (int i = 0; i < 4; ++i)
#pragma unroll
            for (int j = 0; j < NJ; ++j)
#pragma unroll
                for (int r = 0; r < 4; ++r)
                    Ct[(wrow + i * 16 + lhi * 4 + r) * 130 + (wcol + j * 16 + l15)] =
                        f2bf(acc[i][j][r]);
        __syncthreads();
        int l = tid & 63, wv = tid >> 6;
        int sig = (l & 32) | ((l & 4) << 2) | ((l & 24) >> 1) | (l & 3);
        int b = row0 >> 11, n0 = row0 & 2047;
        int h0 = (col0 - 2048) >> 6;
        for (int c = wv * 64; c < wv * 64 + 64; ++c) {
            int ntl = c & 1, hl = (c >> 1) & 1, d = c >> 2;
            unsigned short v = Ct[(ntl * 64 + sig) * 130 + hl * 64 + d];
            vt[((size_t)(b * NHEADS + h0 + hl) * DH + d) * SEQ + n0 + ntl * 64 + l] = v;
        }
        return;
    }
#pragma unroll
    for (int i = 0; i < 4; ++i)
#pragma unroll
        for (int j = 0; j < NJ; ++j)
#pragma unroll
            for (int r = 0; r < 4; ++r) {
                int row = row0 + wrow + i * 16 + lhi * 4 + r;
                int col = col0 + wcol + j * 16 + l15;
                float v = acc[i][j][r];
                if (BIAS) v += bias[col];
                if (GELU_) v = 0.5f * v * (1.0f + erff(v * 0.70710678118f));
                if (RESID == 1) v += ((const float*)resid)[(size_t)row * N + col];
                if (RESID == 2) v += bf2f(((const unsigned short*)resid)[(size_t)row * N + col]);
                if (OBF)
                    ((unsigned short*)C)[(size_t)row * N + col] = f2bf(v);
                else
                    ((float*)C)[(size_t)row * N + col] = v;
            }
}

// ---------- flash attention (R6 structure): 16 q/wave, 64 q/block, direct output ----------
__global__ __launch_bounds__(256) void attn_kernel(const unsigned short* __restrict__ qkv,
                                                   const unsigned short* __restrict__ vt,
                                                   unsigned short* __restrict__ o) {
    __shared__ unsigned short Ks[2][64 * 64];
    __shared__ unsigned short Vs[2][64 * 64];
    int tid = threadIdx.x;
    int lane = tid & 63, w = tid >> 6;
    int l15 = lane & 15, lhi = lane >> 4;
    int wg = blockIdx.x;  // 1024 blocks, 4/CU
    int swz = (wg & 7) * 128 + (wg >> 3);  // 128 consecutive per XCD (4 heads' K/V per L2)
    int qt = swz & 31, h = (swz >> 5) & 15, b = swz >> 9;
    // wave w owns q rows [qt*64 + w*16, +16); Q pre-scaled by 0.125*log2e via weights
    const unsigned short* qb =
        qkv + (size_t)(b * SEQ + qt * 64 + w * 16 + l15) * 3072 + h * DH;
    bf16x8 qf0 = *(const bf16x8*)(qb + lhi * 8);
    bf16x8 qf1 = *(const bf16x8*)(qb + 32 + lhi * 8);
    f32x4 zero = {0.f, 0.f, 0.f, 0.f};
    f32x4 oacc[4], lacc = zero;
#pragma unroll
    for (int i = 0; i < 4; ++i) oacc[i] = zero;
    const short one_s = (short)0x3F80;  // bf16 1.0
    bf16x8 ones = {one_s, one_s, one_s, one_s, one_s, one_s, one_s, one_s};
    // staging: dest linear, source 16B-unit XOR-swizzled with row&7
    int srow = tid >> 3;
    int scx = (tid & 7) ^ (srow & 7);
    const unsigned short* kb = qkv + (size_t)b * SEQ * 3072 + 1024 + h * DH;
    const unsigned short* vb = vt + (size_t)(b * NHEADS + h) * DH * SEQ;
    const unsigned short* k0 = kb + (size_t)srow * 3072 + scx * 8;
    const unsigned short* v0 = vb + (size_t)srow * SEQ + scx * 8;
    auto stage = [&](int buf, int kt) {
        unsigned short* lk = &Ks[buf][0] + tid * 8;
        unsigned short* lv = &Vs[buf][0] + tid * 8;
        gld16(k0 + (size_t)kt * 64 * 3072, lk);
        gld16(k0 + ((size_t)kt * 64 + 32) * 3072, lk + 2048);
        gld16(v0 + kt * 64, lv);
        gld16(v0 + (size_t)32 * SEQ + kt * 64, lv + 2048);
    };
    const int NT = SEQ / 64;
    stage(0, 0);
    asm volatile("s_waitcnt vmcnt(0)" ::: "memory");
    __builtin_amdgcn_s_barrier();
    __builtin_amdgcn_sched_barrier(0);
    int kx = l15 & 7;
    for (int kt = 0; kt < NT; ++kt) {
        int cur = kt & 1;
        if (kt + 1 < NT) stage(cur ^ 1, kt + 1);
        const unsigned short* Kc = &Ks[cur][0];
        const unsigned short* Vc = &Vs[cur][0];
        // S^T = K @ Q^T : lane holds S[kv=16nt+4lhi+r][q=l15]
        f32x4 sacc[4];
#pragma unroll
        for (int nt = 0; nt < 4; ++nt) {
            bf16x8 kf0 = *(const bf16x8*)&Kc[(nt * 16 + l15) * 64 + ((lhi ^ kx) * 8)];
            bf16x8 kf1 = *(const bf16x8*)&Kc[(nt * 16 + l15) * 64 + (((4 + lhi) ^ kx) * 8)];
            f32x4 z = __builtin_amdgcn_mfma_f32_16x16x32_bf16(kf0, qf0, zero, 0, 0, 0);
            sacc[nt] = __builtin_amdgcn_mfma_f32_16x16x32_bf16(kf1, qf1, z, 0, 0, 0);
        }
        // P = exp2(S) (scale pre-folded into Q), packed lane-local via sigma-permuted V
        bf16x8 pf[2];
#pragma unroll
        for (int kc = 0; kc < 2; ++kc) {
            union { bf16x8 v; unsigned int u[4]; } pu;
            pu.u[0] = cvt_pk_bf16(fexp2(sacc[2 * kc][0]), fexp2(sacc[2 * kc][1]));
            pu.u[1] = cvt_pk_bf16(fexp2(sacc[2 * kc][2]), fexp2(sacc[2 * kc][3]));
            pu.u[2] = cvt_pk_bf16(fexp2(sacc[2 * kc + 1][0]), fexp2(sacc[2 * kc + 1][1]));
            pu.u[3] = cvt_pk_bf16(fexp2(sacc[2 * kc + 1][2]), fexp2(sacc[2 * kc + 1][3]));
            pf[kc] = pu.v;
        }
        // O^T += V^T @ P^T ; l += ones @ P^T
#pragma unroll
        for (int dt = 0; dt < 4; ++dt)
#pragma unroll
            for (int kc = 0; kc < 2; ++kc) {
                bf16x8 vf = *(const bf16x8*)&Vc[(dt * 16 + l15) * 64 + (((kc * 4 + lhi) ^ kx) * 8)];
                oacc[dt] = __builtin_amdgcn_mfma_f32_16x16x32_bf16(vf, pf[kc], oacc[dt], 0, 0, 0);
            }
        lacc = __builtin_amdgcn_mfma_f32_16x16x32_bf16(ones, pf[0], lacc, 0, 0, 0);
        lacc = __builtin_amdgcn_mfma_f32_16x16x32_bf16(ones, pf[1], lacc, 0, 0, 0);
        __builtin_amdgcn_sched_barrier(0);
        if (kt + 1 < NT) {
            asm volatile("s_waitcnt vmcnt(0)" ::: "memory");
            __builtin_amdgcn_s_barrier();
            __builtin_amdgcn_sched_barrier(0);
        }
    }
    float rl = 1.0f / lacc[0];
    size_t orow = (size_t)(b * SEQ + qt * 64 + w * 16 + l15) * DIM + h * DH;
#pragma unroll
    for (int dt = 0; dt < 4; ++dt) {
        ushort4 st;
        st.x = f2bf(oacc[dt][0] * rl);
        st.y = f2bf(oacc[dt][1] * rl);
        st.z = f2bf(oacc[dt][2] * rl);
        st.w = f2bf(oacc[dt][3] * rl);
        *(ushort4*)(o + orow + dt * 16 + lhi * 4) = st;
    }
}

extern "C" void kernel_launch(void* const* d_in, const int* in_sizes, int n_in,
                              void* d_out, int out_size, void* d_ws, size_t ws_size,
                              hipStream_t stream) {
    (void)in_sizes; (void)n_in; (void)out_size; (void)ws_size;
    const float* x = (const float*)d_in[0];
    const float* w_qkv = (const float*)d_in[1];
    const float* w_out = (const float*)d_in[2];
    const float* b_out = (const float*)d_in[3];
    const float* g1 = (const float*)d_in[4];
    const float* bt1 = (const float*)d_in[5];
    const float* g2 = (const float*)d_in[6];
    const float* bt2 = (const float*)d_in[7];
    const float* w1 = (const float*)d_in[8];
    const float* b1 = (const float*)d_in[9];
    const float* w2 = (const float*)d_in[10];
    const float* b2 = (const float*)d_in[11];
    float* out = (float*)d_out;

    char* ws = (char*)d_ws;
    size_t off = 0;
    auto alloc = [&](size_t bytes) {
        void* p = ws + off;
        off += (bytes + 255) & ~(size_t)255;
        return p;
    };
    const int R = 2 * SEQ;  // 4096 rows
    unsigned short* xl    = (unsigned short*)alloc((size_t)R * DIM * 2);
    unsigned short* wqkvT = (unsigned short*)alloc((size_t)3 * DIM * DIM * 2);
    unsigned short* woutT = (unsigned short*)alloc((size_t)DIM * DIM * 2);
    unsigned short* w1T   = (unsigned short*)alloc((size_t)DIM * DIM * 2);
    unsigned short* w2T   = (unsigned short*)alloc((size_t)DIM * DIM * 2);
    unsigned short* qkvb  = (unsigned short*)alloc((size_t)R * 3 * DIM * 2);
    unsigned short* vtb   = (unsigned short*)alloc((size_t)R * DIM * 2);
    unsigned short* attO  = (unsigned short*)alloc((size_t)R * DIM * 2);
    unsigned short* outb  = (unsigned short*)alloc((size_t)R * DIM * 2);  // residual stream (bf16)
    unsigned short* h2    = (unsigned short*)alloc((size_t)R * DIM * 2);
    unsigned short* ffn1  = (unsigned short*)alloc((size_t)R * DIM * 2);

    const float CS = 0.125f * 1.44269504f;  // attn scale * log2(e), folded into Q weights
    wtrans_ln<<<dim3(128, 32, 5), 256, 0, stream>>>(w_qkv, w_out, w1, w2, wqkvT, woutT, w1T, w2T,
                                                    CS, x, g1, bt1, xl);

    const unsigned int SH_QKV = (3 * 128 * 32 + 3 * 128 * 32) * 2;   // 48 KB (>= 128*130*2)
    const unsigned int SH_FFN = (3 * 128 * 64 + 3 * 64 * 64) * 2;    // 72 KB
    gemm_kernel<128, 32, 1, 0, 0, 0, 1>
        <<<dim3((3 * DIM / 128) * (R / 128)), 256, SH_QKV, stream>>>(
            xl, wqkvT, qkvb, nullptr, nullptr, vtb, R, 3 * DIM, DIM, 3 * DIM / 128);
    attn_kernel<<<2 * NHEADS * (SEQ / 64), 256, 0, stream>>>(qkvb, vtb, attO);
    gemm_kernel<64, 64, 1, 1, 0, 1, 0><<<dim3((DIM / 64) * (R / 128)), 256, SH_FFN, stream>>>(
        attO, woutT, outb, b_out, x, nullptr, R, DIM, DIM, DIM / 64);
    ln_bf16<<<R, 256, 0, stream>>>(outb, g2, bt2, h2);
    gemm_kernel<64, 64, 1, 1, 1, 0, 0><<<dim3((DIM / 64) * (R / 128)), 256, SH_FFN, stream>>>(
        h2, w1T, ffn1, b1, nullptr, nullptr, R, DIM, DIM, DIM / 64);
    gemm_kernel<64, 64, 0, 1, 0, 2, 0><<<dim3((DIM / 64) * (R / 128)), 256, SH_FFN, stream>>>(
        ffn1, w2T, out, b2, outb, nullptr, R, DIM, DIM, DIM / 64);
}

// Round 15
// 160.245 us; speedup vs baseline: 1.1025x; 1.0006x over previous
//
#include <hip/hip_runtime.h>
#include <math.h>

typedef __attribute__((ext_vector_type(4))) float f32x4;
typedef __attribute__((ext_vector_type(8))) short bf16x8;
typedef __attribute__((ext_vector_type(8))) unsigned short u16x8;

#define DIM 1024
#define SEQ 2048
#define NHEADS 16
#define DH 64

__device__ __forceinline__ unsigned short f2bf(float f) {
    unsigned int u = __builtin_bit_cast(unsigned int, f);
    u += 0x7fffu + ((u >> 16) & 1u);
    return (unsigned short)(u >> 16);
}

__device__ __forceinline__ float bf2f(unsigned short s) {
    unsigned int u = (unsigned int)s << 16;
    return __builtin_bit_cast(float, u);
}

__device__ __forceinline__ unsigned int cvt_pk_bf16(float lo, float hi) {
    unsigned int r;
    asm("v_cvt_pk_bf16_f32 %0, %1, %2" : "=v"(r) : "v"(lo), "v"(hi));
    return r;
}

__device__ __forceinline__ float fexp2(float x) {
    float r;
    asm("v_exp_f32 %0, %1" : "=v"(r) : "v"(x));
    return r;
}

__device__ __forceinline__ void gld16(const unsigned short* g, unsigned short* l) {
    __builtin_amdgcn_global_load_lds((const __attribute__((address_space(1))) void*)g,
                                     (__attribute__((address_space(3))) void*)l, 16, 0, 0);
}

// ---------- weight transposes (z=0..3) + LayerNorm1 (z=4) in one launch ----------
__global__ __launch_bounds__(256) void wtrans_ln(const float* __restrict__ wq,
                                                 const float* __restrict__ wo,
                                                 const float* __restrict__ wf1,
                                                 const float* __restrict__ wf2,
                                                 unsigned short* __restrict__ oq,
                                                 unsigned short* __restrict__ oo,
                                                 unsigned short* __restrict__ of1,
                                                 unsigned short* __restrict__ of2, float sc,
                                                 const float* __restrict__ x,
                                                 const float* __restrict__ g1,
                                                 const float* __restrict__ bt1,
                                                 unsigned short* __restrict__ xl) {
    int z = blockIdx.z;
    int bxi = blockIdx.x;
    int tid = threadIdx.x;
    if (z == 4) {  // LayerNorm over x rows
        int row = blockIdx.y * 128 + bxi;
        const float4* xr = (const float4*)(x + (size_t)row * DIM);
        float4 v = xr[tid];
        float s1 = v.x + v.y + v.z + v.w;
        float s2 = v.x * v.x + v.y * v.y + v.z * v.z + v.w * v.w;
#pragma unroll
        for (int m = 32; m >= 1; m >>= 1) {
            s1 += __shfl_xor(s1, m);
            s2 += __shfl_xor(s2, m);
        }
        __shared__ float r1[4], r2[4];
        int w = tid >> 6;
        if ((tid & 63) == 0) { r1[w] = s1; r2[w] = s2; }
        __syncthreads();
        s1 = r1[0] + r1[1] + r1[2] + r1[3];
        s2 = r2[0] + r2[1] + r2[2] + r2[3];
        float mu = s1 * (1.0f / DIM);
        float var = s2 * (1.0f / DIM) - mu * mu;
        float rstd = rsqrtf(var + 1e-5f);
        float4 g4 = ((const float4*)g1)[tid];
        float4 b4 = ((const float4*)bt1)[tid];
        ushort4 ov;
        ov.x = f2bf((v.x - mu) * rstd * g4.x + b4.x);
        ov.y = f2bf((v.y - mu) * rstd * g4.y + b4.y);
        ov.z = f2bf((v.z - mu) * rstd * g4.z + b4.z);
        ov.w = f2bf((v.w - mu) * rstd * g4.w + b4.w);
        *(ushort4*)(xl + (size_t)row * DIM + tid * 4) = ov;
        return;
    }
    if (bxi >= (z == 0 ? 96 : 32)) return;
    const float* w = z == 0 ? wq : z == 1 ? wo : z == 2 ? wf1 : wf2;
    unsigned short* wt = z == 0 ? oq : z == 1 ? oo : z == 2 ? of1 : of2;
    int N = z == 0 ? 3072 : 1024;
    int scale_n = z == 0 ? 1024 : 0;
    const int K = 1024;
    __shared__ float t[32][33];
    int n0 = bxi * 32, k0 = blockIdx.y * 32;
    int c = tid & 31, rb = tid >> 5;
#pragma unroll
    for (int i = 0; i < 4; ++i) {
        int r = rb + i * 8;
        t[r][c] = w[(size_t)(k0 + r) * N + n0 + c];
    }
    __syncthreads();
#pragma unroll
    for (int i = 0; i < 4; ++i) {
        int r = rb + i * 8;  // N-local
        float v = t[c][r];
        if (n0 + r < scale_n) v *= sc;
        wt[(size_t)(n0 + r) * K + k0 + c] = f2bf(v);
    }
}

// ---------- LayerNorm: bf16 in -> bf16 out ----------
__global__ __launch_bounds__(256) void ln_bf16(const unsigned short* __restrict__ x,
                                               const float* __restrict__ g,
                                               const float* __restrict__ bt,
                                               unsigned short* __restrict__ o) {
    int row = blockIdx.x, tid = threadIdx.x;
    ushort4 v4 = *(const ushort4*)(x + (size_t)row * DIM + tid * 4);
    float vx = bf2f(v4.x), vy = bf2f(v4.y), vz = bf2f(v4.z), vw = bf2f(v4.w);
    float s1 = vx + vy + vz + vw;
    float s2 = vx * vx + vy * vy + vz * vz + vw * vw;
#pragma unroll
    for (int m = 32; m >= 1; m >>= 1) {
        s1 += __shfl_xor(s1, m);
        s2 += __shfl_xor(s2, m);
    }
    __shared__ float r1[4], r2[4];
    int w = tid >> 6;
    if ((tid & 63) == 0) { r1[w] = s1; r2[w] = s2; }
    __syncthreads();
    s1 = r1[0] + r1[1] + r1[2] + r1[3];
    s2 = r2[0] + r2[1] + r2[2] + r2[3];
    float mu = s1 * (1.0f / DIM);
    float var = s2 * (1.0f / DIM) - mu * mu;
    float rstd = rsqrtf(var + 1e-5f);
    float4 g4 = ((const float4*)g)[tid];
    float4 b4 = ((const float4*)bt)[tid];
    ushort4 ov;
    ov.x = f2bf((vx - mu) * rstd * g4.x + b4.x);
    ov.y = f2bf((vy - mu) * rstd * g4.y + b4.y);
    ov.z = f2bf((vz - mu) * rstd * g4.z + b4.z);
    ov.w = f2bf((vw - mu) * rstd * g4.w + b4.w);
    *(ushort4*)(o + (size_t)row * DIM + tid * 4) = ov;
}

// ---------- GEMM, 3-buffer counted-vmcnt pipeline, XOR-swizzled LDS ----------
// C[M,N] = A[M,K](bf16) @ BT[N,K](bf16)^T. BM=128.
// VT=1: blocks with col0>=2048 write sigma-permuted transposed V to vt instead of C.
// RESID: 0=none, 1=f32 resid, 2=bf16 resid.
// Row-hash: U=4 uses (rr ^ rr>>2)&3 (plain rr&3 leaves a 4-way bank conflict since
// row stride is 64B = half a bank rotation); U=8 uses rr&7 (128B rows, already 2-way-free).
template <int BN, int BK, int OBF, int BIAS, int GELU_, int RESID, int VT>
__global__ __launch_bounds__(256) void gemm_kernel(const unsigned short* __restrict__ A,
                                                   const unsigned short* __restrict__ BT,
                                                   void* __restrict__ C,
                                                   const float* __restrict__ bias,
                                                   const void* __restrict__ resid,
                                                   unsigned short* __restrict__ vt,
                                                   int M, int N, int K, int nbx) {
    constexpr int U = BK / 8;              // 16B units per row
    constexpr int NAU = 128 * U;           // A-tile units
    constexpr int NBU = BN * U;            // B-tile units
    constexpr int PT = (NAU + NBU) / 256;  // gld16 per thread per stage
    constexpr int NJ = BN / 32;
    constexpr int KK = BK / 32;
    extern __shared__ char smem[];
    unsigned short* As = (unsigned short*)smem;      // [3][128*BK]
    unsigned short* Bs = As + 3 * 128 * BK;          // [3][BN*BK]
    int tid = threadIdx.x;
    int lane = tid & 63, w = tid >> 6;
    int l15 = lane & 15, lhi = lane >> 4;
    int nwg = gridDim.x, wg = blockIdx.x;
    int swz = (wg & 7) * (nwg >> 3) + (wg >> 3);  // XCD-chunked (nwg % 8 == 0)
    int bx = swz % nbx, by = swz / nbx;
    int row0 = by * 128, col0 = bx * BN;
    int wrow = (w >> 1) * 64, wcol = (w & 1) * (16 * NJ);
    auto rh = [](int rr) -> int {  // row hash for XOR swizzle (conflict-free both U)
        if constexpr (U == 4) return (rr ^ (rr >> 2)) & 3;
        else return rr & (U - 1);
    };
    f32x4 zero = {0.f, 0.f, 0.f, 0.f};
    f32x4 acc[4][NJ];
#pragma unroll
    for (int i = 0; i < 4; ++i)
#pragma unroll
        for (int j = 0; j < NJ; ++j) acc[i][j] = zero;
    auto stage = [&](int buf, int kt) {
#pragma unroll
        for (int p = 0; p < PT; ++p) {
            if (p * 256 < NAU) {
                int u = tid + p * 256;
                int r = u / U, cu = u % U;
                int scu = cu ^ rh(r);
                gld16(A + (size_t)(row0 + r) * K + kt * BK + scu * 8, As + buf * 128 * BK + u * 8);
            } else {
                int ub = tid + p * 256 - NAU;
                int r = ub / U, cu = ub % U;
                int scu = cu ^ rh(r);
                gld16(BT + (size_t)(col0 + r) * K + kt * BK + scu * 8, Bs + buf * BN * BK + ub * 8);
            }
        }
    };
    int nk = K / BK;
    stage(0, 0);
    stage(1, 1);
    asm volatile("s_waitcnt vmcnt(%0)" ::"i"(PT) : "memory");
    __builtin_amdgcn_s_barrier();
    __builtin_amdgcn_sched_barrier(0);
    int cur = 0;
    for (int kt = 0; kt < nk; ++kt) {
        int nxt2 = cur + 2 >= 3 ? cur - 1 : cur + 2;
        if (kt + 2 < nk) stage(nxt2, kt + 2);
        const unsigned short* Ab = As + cur * 128 * BK;
        const unsigned short* Bb = Bs + cur * BN * BK;
        bf16x8 af[4][KK], bfr[NJ][KK];
#pragma unroll
        for (int i = 0; i < 4; ++i)
#pragma unroll
            for (int kk = 0; kk < KK; ++kk) {
                int rr = wrow + i * 16 + l15;
                int up = (kk * 4 + lhi) ^ rh(rr);
                af[i][kk] = *(const bf16x8*)&Ab[rr * BK + up * 8];
            }
#pragma unroll
        for (int j = 0; j < NJ; ++j)
#pragma unroll
            for (int kk = 0; kk < KK; ++kk) {
                int rr = wcol + j * 16 + l15;
                int up = (kk * 4 + lhi) ^ rh(rr);
                bfr[j][kk] = *(const bf16x8*)&Bb[rr * BK + up * 8];
            }
#pragma unroll
        for (int kk = 0; kk < KK; ++kk)
#pragma unroll
            for (int i = 0; i < 4; ++i)
#pragma unroll
                for (int j = 0; j < NJ; ++j)
                    acc[i][j] = __builtin_amdgcn_mfma_f32_16x16x32_bf16(af[i][kk], bfr[j][kk],
                                                                        acc[i][j], 0, 0, 0);
        __builtin_amdgcn_sched_barrier(0);
        if (kt + 1 < nk) {
            if (kt + 2 < nk)
                asm volatile("s_waitcnt vmcnt(%0)" ::"i"(PT) : "memory");
            else
                asm volatile("s_waitcnt vmcnt(0)" ::: "memory");
            __builtin_amdgcn_s_barrier();
            __builtin_amdgcn_sched_barrier(0);
        }
        cur = cur + 1 == 3 ? 0 : cur + 1;
    }
    if (VT && col0 >= 2048) {
        // V block: transpose + sigma-permute into vt[b,h][d][n]; skip normal C write.
        __syncthreads();  // all waves done with staging LDS
        unsigned short* Ct = (unsigned short*)smem;  // [128][130] bf16 (33280 B)
#pragma unroll
        for (int i = 0; i < 4; ++i)
#pragma unroll
            for (int j = 0; j < NJ; ++j)
#pragma unroll
                for (int r = 0; r < 4; ++r)
                    Ct[(wrow + i * 16 + lhi * 4 + r) * 130 + (wcol + j * 16 + l15)] =
                        f2bf(acc[i][j][r]);
        __syncthreads();
        int l = tid & 63, wv = tid >> 6;
        int sig = (l & 32) | ((l & 4) << 2) | ((l & 24) >> 1) | (l & 3);
        int b = row0 >> 11, n0 = row0 & 2047;
        int h0 = (col0 - 2048) >> 6;
        for (int c = wv * 64; c < wv * 64 + 64; ++c) {
            int ntl = c & 1, hl = (c >> 1) & 1, d = c >> 2;
            unsigned short v = Ct[(ntl * 64 + sig) * 130 + hl * 64 + d];
            vt[((size_t)(b * NHEADS + h0 + hl) * DH + d) * SEQ + n0 + ntl * 64 + l] = v;
        }
        return;
    }
#pragma unroll
    for (int i = 0; i < 4; ++i)
#pragma unroll
        for (int j = 0; j < NJ; ++j)
#pragma unroll
            for (int r = 0; r < 4; ++r) {
                int row = row0 + wrow + i * 16 + lhi * 4 + r;
                int col = col0 + wcol + j * 16 + l15;
                float v = acc[i][j][r];
                if (BIAS) v += bias[col];
                if (GELU_) v = 0.5f * v * (1.0f + erff(v * 0.70710678118f));
                if (RESID == 1) v += ((const float*)resid)[(size_t)row * N + col];
                if (RESID == 2) v += bf2f(((const unsigned short*)resid)[(size_t)row * N + col]);
                if (OBF)
                    ((unsigned short*)C)[(size_t)row * N + col] = f2bf(v);
                else
                    ((float*)C)[(size_t)row * N + col] = v;
            }
}

// ---------- flash attention (R6 structure): 16 q/wave, 64 q/block, direct output ----------
__global__ __launch_bounds__(256) void attn_kernel(const unsigned short* __restrict__ qkv,
                                                   const unsigned short* __restrict__ vt,
                                                   unsigned short* __restrict__ o) {
    __shared__ unsigned short Ks[2][64 * 64];
    __shared__ unsigned short Vs[2][64 * 64];
    int tid = threadIdx.x;
    int lane = tid & 63, w = tid >> 6;
    int l15 = lane & 15, lhi = lane >> 4;
    int wg = blockIdx.x;  // 1024 blocks, 4/CU
    int swz = (wg & 7) * 128 + (wg >> 3);  // 128 consecutive per XCD (4 heads' K/V per L2)
    int qt = swz & 31, h = (swz >> 5) & 15, b = swz >> 9;
    // wave w owns q rows [qt*64 + w*16, +16); Q pre-scaled by 0.125*log2e via weights
    const unsigned short* qb =
        qkv + (size_t)(b * SEQ + qt * 64 + w * 16 + l15) * 3072 + h * DH;
    bf16x8 qf0 = *(const bf16x8*)(qb + lhi * 8);
    bf16x8 qf1 = *(const bf16x8*)(qb + 32 + lhi * 8);
    f32x4 zero = {0.f, 0.f, 0.f, 0.f};
    f32x4 oacc[4], lacc = zero;
#pragma unroll
    for (int i = 0; i < 4; ++i) oacc[i] = zero;
    const short one_s = (short)0x3F80;  // bf16 1.0
    bf16x8 ones = {one_s, one_s, one_s, one_s, one_s, one_s, one_s, one_s};
    // staging: dest linear, source 16B-unit XOR-swizzled with row&7
    int srow = tid >> 3;
    int scx = (tid & 7) ^ (srow & 7);
    const unsigned short* kb = qkv + (size_t)b * SEQ * 3072 + 1024 + h * DH;
    const unsigned short* vb = vt + (size_t)(b * NHEADS + h) * DH * SEQ;
    const unsigned short* k0 = kb + (size_t)srow * 3072 + scx * 8;
    const unsigned short* v0 = vb + (size_t)srow * SEQ + scx * 8;
    auto stage = [&](int buf, int kt) {
        unsigned short* lk = &Ks[buf][0] + tid * 8;
        unsigned short* lv = &Vs[buf][0] + tid * 8;
        gld16(k0 + (size_t)kt * 64 * 3072, lk);
        gld16(k0 + ((size_t)kt * 64 + 32) * 3072, lk + 2048);
        gld16(v0 + kt * 64, lv);
        gld16(v0 + (size_t)32 * SEQ + kt * 64, lv + 2048);
    };
    const int NT = SEQ / 64;
    stage(0, 0);
    asm volatile("s_waitcnt vmcnt(0)" ::: "memory");
    __builtin_amdgcn_s_barrier();
    __builtin_amdgcn_sched_barrier(0);
    int kx = l15 & 7;
    for (int kt = 0; kt < NT; ++kt) {
        int cur = kt & 1;
        if (kt + 1 < NT) stage(cur ^ 1, kt + 1);
        const unsigned short* Kc = &Ks[cur][0];
        const unsigned short* Vc = &Vs[cur][0];
        // S^T = K @ Q^T : lane holds S[kv=16nt+4lhi+r][q=l15]
        f32x4 sacc[4];
#pragma unroll
        for (int nt = 0; nt < 4; ++nt) {
            bf16x8 kf0 = *(const bf16x8*)&Kc[(nt * 16 + l15) * 64 + ((lhi ^ kx) * 8)];
            bf16x8 kf1 = *(const bf16x8*)&Kc[(nt * 16 + l15) * 64 + (((4 + lhi) ^ kx) * 8)];
            f32x4 z = __builtin_amdgcn_mfma_f32_16x16x32_bf16(kf0, qf0, zero, 0, 0, 0);
            sacc[nt] = __builtin_amdgcn_mfma_f32_16x16x32_bf16(kf1, qf1, z, 0, 0, 0);
        }
        // P = exp2(S) (scale pre-folded into Q), packed lane-local via sigma-permuted V
        bf16x8 pf[2];
#pragma unroll
        for (int kc = 0; kc < 2; ++kc) {
            union { bf16x8 v; unsigned int u[4]; } pu;
            pu.u[0] = cvt_pk_bf16(fexp2(sacc[2 * kc][0]), fexp2(sacc[2 * kc][1]));
            pu.u[1] = cvt_pk_bf16(fexp2(sacc[2 * kc][2]), fexp2(sacc[2 * kc][3]));
            pu.u[2] = cvt_pk_bf16(fexp2(sacc[2 * kc + 1][0]), fexp2(sacc[2 * kc + 1][1]));
            pu.u[3] = cvt_pk_bf16(fexp2(sacc[2 * kc + 1][2]), fexp2(sacc[2 * kc + 1][3]));
            pf[kc] = pu.v;
        }
        // O^T += V^T @ P^T ; l += ones @ P^T
#pragma unroll
        for (int dt = 0; dt < 4; ++dt)
#pragma unroll
            for (int kc = 0; kc < 2; ++kc) {
                bf16x8 vf = *(const bf16x8*)&Vc[(dt * 16 + l15) * 64 + (((kc * 4 + lhi) ^ kx) * 8)];
                oacc[dt] = __builtin_amdgcn_mfma_f32_16x16x32_bf16(vf, pf[kc], oacc[dt], 0, 0, 0);
            }
        lacc = __builtin_amdgcn_mfma_f32_16x16x32_bf16(ones, pf[0], lacc, 0, 0, 0);
        lacc = __builtin_amdgcn_mfma_f32_16x16x32_bf16(ones, pf[1], lacc, 0, 0, 0);
        __builtin_amdgcn_sched_barrier(0);
        if (kt + 1 < NT) {
            asm volatile("s_waitcnt vmcnt(0)" ::: "memory");
            __builtin_amdgcn_s_barrier();
            __builtin_amdgcn_sched_barrier(0);
        }
    }
    float rl = 1.0f / lacc[0];
    size_t orow = (size_t)(b * SEQ + qt * 64 + w * 16 + l15) * DIM + h * DH;
#pragma unroll
    for (int dt = 0; dt < 4; ++dt) {
        ushort4 st;
        st.x = f2bf(oacc[dt][0] * rl);
        st.y = f2bf(oacc[dt][1] * rl);
        st.z = f2bf(oacc[dt][2] * rl);
        st.w = f2bf(oacc[dt][3] * rl);
        *(ushort4*)(o + orow + dt * 16 + lhi * 4) = st;
    }
}

extern "C" void kernel_launch(void* const* d_in, const int* in_sizes, int n_in,
                              void* d_out, int out_size, void* d_ws, size_t ws_size,
                              hipStream_t stream) {
    (void)in_sizes; (void)n_in; (void)out_size; (void)ws_size;
    const float* x = (const float*)d_in[0];
    const float* w_qkv = (const float*)d_in[1];
    const float* w_out = (const float*)d_in[2];
    const float* b_out = (const float*)d_in[3];
    const float* g1 = (const float*)d_in[4];
    const float* bt1 = (const float*)d_in[5];
    const float* g2 = (const float*)d_in[6];
    const float* bt2 = (const float*)d_in[7];
    const float* w1 = (const float*)d_in[8];
    const float* b1 = (const float*)d_in[9];
    const float* w2 = (const float*)d_in[10];
    const float* b2 = (const float*)d_in[11];
    float* out = (float*)d_out;

    char* ws = (char*)d_ws;
    size_t off = 0;
    auto alloc = [&](size_t bytes) {
        void* p = ws + off;
        off += (bytes + 255) & ~(size_t)255;
        return p;
    };
    const int R = 2 * SEQ;  // 4096 rows
    unsigned short* xl    = (unsigned short*)alloc((size_t)R * DIM * 2);
    unsigned short* wqkvT = (unsigned short*)alloc((size_t)3 * DIM * DIM * 2);
    unsigned short* woutT = (unsigned short*)alloc((size_t)DIM * DIM * 2);
    unsigned short* w1T   = (unsigned short*)alloc((size_t)DIM * DIM * 2);
    unsigned short* w2T   = (unsigned short*)alloc((size_t)DIM * DIM * 2);
    unsigned short* qkvb  = (unsigned short*)alloc((size_t)R * 3 * DIM * 2);
    unsigned short* vtb   = (unsigned short*)alloc((size_t)R * DIM * 2);
    unsigned short* attO  = (unsigned short*)alloc((size_t)R * DIM * 2);
    unsigned short* outb  = (unsigned short*)alloc((size_t)R * DIM * 2);  // residual stream (bf16)
    unsigned short* h2    = (unsigned short*)alloc((size_t)R * DIM * 2);
    unsigned short* ffn1  = (unsigned short*)alloc((size_t)R * DIM * 2);

    const float CS = 0.125f * 1.44269504f;  // attn scale * log2(e), folded into Q weights
    wtrans_ln<<<dim3(128, 32, 5), 256, 0, stream>>>(w_qkv, w_out, w1, w2, wqkvT, woutT, w1T, w2T,
                                                    CS, x, g1, bt1, xl);

    const unsigned int SH_QKV = (3 * 128 * 32 + 3 * 128 * 32) * 2;   // 48 KB (>= 128*130*2)
    const unsigned int SH_FFN = (3 * 128 * 64 + 3 * 64 * 64) * 2;    // 72 KB
    gemm_kernel<128, 32, 1, 0, 0, 0, 1>
        <<<dim3((3 * DIM / 128) * (R / 128)), 256, SH_QKV, stream>>>(
            xl, wqkvT, qkvb, nullptr, nullptr, vtb, R, 3 * DIM, DIM, 3 * DIM / 128);
    attn_kernel<<<2 * NHEADS * (SEQ / 64), 256, 0, stream>>>(qkvb, vtb, attO);
    gemm_kernel<64, 64, 1, 1, 0, 1, 0><<<dim3((DIM / 64) * (R / 128)), 256, SH_FFN, stream>>>(
        attO, woutT, outb, b_out, x, nullptr, R, DIM, DIM, DIM / 64);
    ln_bf16<<<R, 256, 0, stream>>>(outb, g2, bt2, h2);
    gemm_kernel<64, 64, 1, 1, 1, 0, 0><<<dim3((DIM / 64) * (R / 128)), 256, SH_FFN, stream>>>(
        h2, w1T, ffn1, b1, nullptr, nullptr, R, DIM, DIM, DIM / 64);
    gemm_kernel<64, 64, 0, 1, 0, 2, 0><<<dim3((DIM / 64) * (R / 128)), 256, SH_FFN, stream>>>(
        ffn1, w2T, out, b2, outb, nullptr, R, DIM, DIM, DIM / 64);
}

// Round 16
// 157.199 us; speedup vs baseline: 1.1239x; 1.0194x over previous
//
#include <hip/hip_runtime.h>
#include <math.h>

typedef __attribute__((ext_vector_type(4))) float f32x4;
typedef __attribute__((ext_vector_type(8))) short bf16x8;
typedef __attribute__((ext_vector_type(8))) unsigned short u16x8;

#define DIM 1024
#define SEQ 2048
#define NHEADS 16
#define DH 64

__device__ __forceinline__ unsigned short f2bf(float f) {
    unsigned int u = __builtin_bit_cast(unsigned int, f);
    u += 0x7fffu + ((u >> 16) & 1u);
    return (unsigned short)(u >> 16);
}

__device__ __forceinline__ float bf2f(unsigned short s) {
    unsigned int u = (unsigned int)s << 16;
    return __builtin_bit_cast(float, u);
}

__device__ __forceinline__ unsigned int cvt_pk_bf16(float lo, float hi) {
    unsigned int r;
    asm("v_cvt_pk_bf16_f32 %0, %1, %2" : "=v"(r) : "v"(lo), "v"(hi));
    return r;
}

__device__ __forceinline__ float fexp2(float x) {
    float r;
    asm("v_exp_f32 %0, %1" : "=v"(r) : "v"(x));
    return r;
}

__device__ __forceinline__ void gld16(const unsigned short* g, unsigned short* l) {
    __builtin_amdgcn_global_load_lds((const __attribute__((address_space(1))) void*)g,
                                     (__attribute__((address_space(3))) void*)l, 16, 0, 0);
}

// ---------- weight transposes (z=0..3) + LayerNorm1 (z=4) in one launch ----------
__global__ __launch_bounds__(256) void wtrans_ln(const float* __restrict__ wq,
                                                 const float* __restrict__ wo,
                                                 const float* __restrict__ wf1,
                                                 const float* __restrict__ wf2,
                                                 unsigned short* __restrict__ oq,
                                                 unsigned short* __restrict__ oo,
                                                 unsigned short* __restrict__ of1,
                                                 unsigned short* __restrict__ of2, float sc,
                                                 const float* __restrict__ x,
                                                 const float* __restrict__ g1,
                                                 const float* __restrict__ bt1,
                                                 unsigned short* __restrict__ xl) {
    int z = blockIdx.z;
    int bxi = blockIdx.x;
    int tid = threadIdx.x;
    if (z == 4) {  // LayerNorm over x rows
        int row = blockIdx.y * 128 + bxi;
        const float4* xr = (const float4*)(x + (size_t)row * DIM);
        float4 v = xr[tid];
        float s1 = v.x + v.y + v.z + v.w;
        float s2 = v.x * v.x + v.y * v.y + v.z * v.z + v.w * v.w;
#pragma unroll
        for (int m = 32; m >= 1; m >>= 1) {
            s1 += __shfl_xor(s1, m);
            s2 += __shfl_xor(s2, m);
        }
        __shared__ float r1[4], r2[4];
        int w = tid >> 6;
        if ((tid & 63) == 0) { r1[w] = s1; r2[w] = s2; }
        __syncthreads();
        s1 = r1[0] + r1[1] + r1[2] + r1[3];
        s2 = r2[0] + r2[1] + r2[2] + r2[3];
        float mu = s1 * (1.0f / DIM);
        float var = s2 * (1.0f / DIM) - mu * mu;
        float rstd = rsqrtf(var + 1e-5f);
        float4 g4 = ((const float4*)g1)[tid];
        float4 b4 = ((const float4*)bt1)[tid];
        ushort4 ov;
        ov.x = f2bf((v.x - mu) * rstd * g4.x + b4.x);
        ov.y = f2bf((v.y - mu) * rstd * g4.y + b4.y);
        ov.z = f2bf((v.z - mu) * rstd * g4.z + b4.z);
        ov.w = f2bf((v.w - mu) * rstd * g4.w + b4.w);
        *(ushort4*)(xl + (size_t)row * DIM + tid * 4) = ov;
        return;
    }
    if (bxi >= (z == 0 ? 96 : 32)) return;
    const float* w = z == 0 ? wq : z == 1 ? wo : z == 2 ? wf1 : wf2;
    unsigned short* wt = z == 0 ? oq : z == 1 ? oo : z == 2 ? of1 : of2;
    int N = z == 0 ? 3072 : 1024;
    int scale_n = z == 0 ? 1024 : 0;
    const int K = 1024;
    __shared__ float t[32][33];
    int n0 = bxi * 32, k0 = blockIdx.y * 32;
    int c = tid & 31, rb = tid >> 5;
#pragma unroll
    for (int i = 0; i < 4; ++i) {
        int r = rb + i * 8;
        t[r][c] = w[(size_t)(k0 + r) * N + n0 + c];
    }
    __syncthreads();
#pragma unroll
    for (int i = 0; i < 4; ++i) {
        int r = rb + i * 8;  // N-local
        float v = t[c][r];
        if (n0 + r < scale_n) v *= sc;
        wt[(size_t)(n0 + r) * K + k0 + c] = f2bf(v);
    }
}

// ---------- LayerNorm: bf16 in -> bf16 out ----------
__global__ __launch_bounds__(256) void ln_bf16(const unsigned short* __restrict__ x,
                                               const float* __restrict__ g,
                                               const float* __restrict__ bt,
                                               unsigned short* __restrict__ o) {
    int row = blockIdx.x, tid = threadIdx.x;
    ushort4 v4 = *(const ushort4*)(x + (size_t)row * DIM + tid * 4);
    float vx = bf2f(v4.x), vy = bf2f(v4.y), vz = bf2f(v4.z), vw = bf2f(v4.w);
    float s1 = vx + vy + vz + vw;
    float s2 = vx * vx + vy * vy + vz * vz + vw * vw;
#pragma unroll
    for (int m = 32; m >= 1; m >>= 1) {
        s1 += __shfl_xor(s1, m);
        s2 += __shfl_xor(s2, m);
    }
    __shared__ float r1[4], r2[4];
    int w = tid >> 6;
    if ((tid & 63) == 0) { r1[w] = s1; r2[w] = s2; }
    __syncthreads();
    s1 = r1[0] + r1[1] + r1[2] + r1[3];
    s2 = r2[0] + r2[1] + r2[2] + r2[3];
    float mu = s1 * (1.0f / DIM);
    float var = s2 * (1.0f / DIM) - mu * mu;
    float rstd = rsqrtf(var + 1e-5f);
    float4 g4 = ((const float4*)g)[tid];
    float4 b4 = ((const float4*)bt)[tid];
    ushort4 ov;
    ov.x = f2bf((vx - mu) * rstd * g4.x + b4.x);
    ov.y = f2bf((vy - mu) * rstd * g4.y + b4.y);
    ov.z = f2bf((vz - mu) * rstd * g4.z + b4.z);
    ov.w = f2bf((vw - mu) * rstd * g4.w + b4.w);
    *(ushort4*)(o + (size_t)row * DIM + tid * 4) = ov;
}

// ---------- 256x256 8-wave GEMM for qkv: phase-split, counted-vmcnt ring ----------
// C[M,N] = A[M,K] @ BT[N,K]^T, all bf16. BM=BN=256, BK=64, 512 threads.
__global__ __launch_bounds__(512) void gemm256_qkv(const unsigned short* __restrict__ A,
                                                   const unsigned short* __restrict__ BT,
                                                   unsigned short* __restrict__ C,
                                                   int M, int N, int K, int nbx) {
    __shared__ unsigned short As[2][256 * 64];  // 64 KB
    __shared__ unsigned short Bs[2][256 * 64];  // 64 KB
    int tid = threadIdx.x;
    int lane = tid & 63, w = tid >> 6;
    int l15 = lane & 15, lhi = lane >> 4;
    int wr = w >> 2, wc = w & 3;  // 2M x 4N wave grid; per-wave C = 128x64
    int nwg = gridDim.x, wg = blockIdx.x;
    int swz = (wg & 7) * (nwg >> 3) + (wg >> 3);  // XCD-chunked (192 % 8 == 0)
    int bx = swz % nbx, by = swz / nbx;
    int row0 = by * 256, col0 = bx * 256;
    f32x4 zero = {0.f, 0.f, 0.f, 0.f};
    f32x4 acc[8][4];
#pragma unroll
    for (int i = 0; i < 8; ++i)
#pragma unroll
        for (int j = 0; j < 4; ++j) acc[i][j] = zero;
    auto stageA = [&](int slot, int kt) {
#pragma unroll
        for (int p = 0; p < 4; ++p) {
            int u = tid + p * 512;
            int r = u >> 3, cu = u & 7;
            int scu = cu ^ (r & 7);
            gld16(A + (size_t)(row0 + r) * K + kt * 64 + scu * 8, &As[slot][0] + u * 8);
        }
    };
    auto stageB = [&](int slot, int kt) {
#pragma unroll
        for (int p = 0; p < 4; ++p) {
            int u = tid + p * 512;
            int r = u >> 3, cu = u & 7;
            int scu = cu ^ (r & 7);
            gld16(BT + (size_t)(col0 + r) * K + kt * 64 + scu * 8, &Bs[slot][0] + u * 8);
        }
    };
    int nk = K / 64;  // 16
    // prologue: tiles 0,1 -> slots 0,1 (16 loads/thread); drain tile 0 (keep 8 in flight)
    stageB(0, 0);
    stageA(0, 0);
    stageB(1, 1);
    stageA(1, 1);
    asm volatile("s_waitcnt vmcnt(8)" ::: "memory");
    __builtin_amdgcn_s_barrier();
    __builtin_amdgcn_sched_barrier(0);
    for (int t = 0; t < nk; ++t) {
        int cur = t & 1;
        const unsigned short* Ab = &As[cur][0];
        const unsigned short* Bb = &Bs[cur][0];
        // B-frags for the whole K-tile (read once, held in regs)
        bf16x8 bfr[4][2];
#pragma unroll
        for (int j = 0; j < 4; ++j)
#pragma unroll
            for (int kk = 0; kk < 2; ++kk) {
                int rr = wc * 64 + j * 16 + l15;
                bfr[j][kk] = *(const bf16x8*)&Bb[rr * 64 + (((kk * 4 + lhi) ^ (rr & 7)) * 8)];
            }
#pragma unroll
        for (int q = 0; q < 4; ++q) {
            bf16x8 af[2][2];
#pragma unroll
            for (int i2 = 0; i2 < 2; ++i2)
#pragma unroll
                for (int kk = 0; kk < 2; ++kk) {
                    int rr = wr * 128 + (q * 2 + i2) * 16 + l15;
                    af[i2][kk] = *(const bf16x8*)&Ab[rr * 64 + (((kk * 4 + lhi) ^ (rr & 7)) * 8)];
                }
#pragma unroll
            for (int kk = 0; kk < 2; ++kk)
#pragma unroll
                for (int i2 = 0; i2 < 2; ++i2)
#pragma unroll
                    for (int j = 0; j < 4; ++j)
                        acc[q * 2 + i2][j] = __builtin_amdgcn_mfma_f32_16x16x32_bf16(
                            af[i2][kk], bfr[j][kk], acc[q * 2 + i2][j], 0, 0, 0);
            if (q == 0) {
                // all waves done reading B(cur) (frags + quad0 A in regs) -> B region free
                __builtin_amdgcn_sched_barrier(0);
                __builtin_amdgcn_s_barrier();
                __builtin_amdgcn_sched_barrier(0);
                if (t + 2 < nk) stageB(cur, t + 2);
            }
        }
        // all waves done reading A(cur) -> A region free
        __builtin_amdgcn_sched_barrier(0);
        __builtin_amdgcn_s_barrier();
        __builtin_amdgcn_sched_barrier(0);
        if (t + 2 < nk) stageA(cur, t + 2);
        if (t + 1 < nk) {
            // drain tile t+1's stages (8 loads); keep tile t+2's 8 in flight
            if (t + 2 < nk)
                asm volatile("s_waitcnt vmcnt(8)" ::: "memory");
            else
                asm volatile("s_waitcnt vmcnt(0)" ::: "memory");
            __builtin_amdgcn_s_barrier();
            __builtin_amdgcn_sched_barrier(0);
        }
    }
#pragma unroll
    for (int i = 0; i < 8; ++i)
#pragma unroll
        for (int j = 0; j < 4; ++j)
#pragma unroll
            for (int r = 0; r < 4; ++r) {
                int row = row0 + wr * 128 + i * 16 + lhi * 4 + r;
                int col = col0 + wc * 64 + j * 16 + l15;
                C[(size_t)row * N + col] = f2bf(acc[i][j][r]);
            }
}

// ---------- GEMM, 3-buffer counted-vmcnt pipeline, XOR-swizzled LDS (N=1024 GEMMs) ----------
// RESID: 0=none, 1=f32 resid, 2=bf16 resid.
template <int BN, int BK, int OBF, int BIAS, int GELU_, int RESID>
__global__ __launch_bounds__(256) void gemm_kernel(const unsigned short* __restrict__ A,
                                                   const unsigned short* __restrict__ BT,
                                                   void* __restrict__ C,
                                                   const float* __restrict__ bias,
                                                   const void* __restrict__ resid,
                                                   int M, int N, int K, int nbx) {
    constexpr int U = BK / 8;
    constexpr int NAU = 128 * U;
    constexpr int NBU = BN * U;
    constexpr int PT = (NAU + NBU) / 256;
    constexpr int NJ = BN / 32;
    constexpr int KK = BK / 32;
    extern __shared__ char smem[];
    unsigned short* As = (unsigned short*)smem;
    unsigned short* Bs = As + 3 * 128 * BK;
    int tid = threadIdx.x;
    int lane = tid & 63, w = tid >> 6;
    int l15 = lane & 15, lhi = lane >> 4;
    int nwg = gridDim.x, wg = blockIdx.x;
    int swz = (wg & 7) * (nwg >> 3) + (wg >> 3);
    int bx = swz % nbx, by = swz / nbx;
    int row0 = by * 128, col0 = bx * BN;
    int wrow = (w >> 1) * 64, wcol = (w & 1) * (16 * NJ);
    auto rh = [](int rr) -> int {
        if constexpr (U == 4) return (rr ^ (rr >> 2)) & 3;
        else return rr & (U - 1);
    };
    f32x4 zero = {0.f, 0.f, 0.f, 0.f};
    f32x4 acc[4][NJ];
#pragma unroll
    for (int i = 0; i < 4; ++i)
#pragma unroll
        for (int j = 0; j < NJ; ++j) acc[i][j] = zero;
    auto stage = [&](int buf, int kt) {
#pragma unroll
        for (int p = 0; p < PT; ++p) {
            if (p * 256 < NAU) {
                int u = tid + p * 256;
                int r = u / U, cu = u % U;
                int scu = cu ^ rh(r);
                gld16(A + (size_t)(row0 + r) * K + kt * BK + scu * 8, As + buf * 128 * BK + u * 8);
            } else {
                int ub = tid + p * 256 - NAU;
                int r = ub / U, cu = ub % U;
                int scu = cu ^ rh(r);
                gld16(BT + (size_t)(col0 + r) * K + kt * BK + scu * 8, Bs + buf * BN * BK + ub * 8);
            }
        }
    };
    int nk = K / BK;
    stage(0, 0);
    stage(1, 1);
    asm volatile("s_waitcnt vmcnt(%0)" ::"i"(PT) : "memory");
    __builtin_amdgcn_s_barrier();
    __builtin_amdgcn_sched_barrier(0);
    int cur = 0;
    for (int kt = 0; kt < nk; ++kt) {
        int nxt2 = cur + 2 >= 3 ? cur - 1 : cur + 2;
        if (kt + 2 < nk) stage(nxt2, kt + 2);
        const unsigned short* Ab = As + cur * 128 * BK;
        const unsigned short* Bb = Bs + cur * BN * BK;
        bf16x8 af[4][KK], bfr[NJ][KK];
#pragma unroll
        for (int i = 0; i < 4; ++i)
#pragma unroll
            for (int kk = 0; kk < KK; ++kk) {
                int rr = wrow + i * 16 + l15;
                int up = (kk * 4 + lhi) ^ rh(rr);
                af[i][kk] = *(const bf16x8*)&Ab[rr * BK + up * 8];
            }
#pragma unroll
        for (int j = 0; j < NJ; ++j)
#pragma unroll
            for (int kk = 0; kk < KK; ++kk) {
                int rr = wcol + j * 16 + l15;
                int up = (kk * 4 + lhi) ^ rh(rr);
                bfr[j][kk] = *(const bf16x8*)&Bb[rr * BK + up * 8];
            }
#pragma unroll
        for (int kk = 0; kk < KK; ++kk)
#pragma unroll
            for (int i = 0; i < 4; ++i)
#pragma unroll
                for (int j = 0; j < NJ; ++j)
                    acc[i][j] = __builtin_amdgcn_mfma_f32_16x16x32_bf16(af[i][kk], bfr[j][kk],
                                                                        acc[i][j], 0, 0, 0);
        __builtin_amdgcn_sched_barrier(0);
        if (kt + 1 < nk) {
            if (kt + 2 < nk)
                asm volatile("s_waitcnt vmcnt(%0)" ::"i"(PT) : "memory");
            else
                asm volatile("s_waitcnt vmcnt(0)" ::: "memory");
            __builtin_amdgcn_s_barrier();
            __builtin_amdgcn_sched_barrier(0);
        }
        cur = cur + 1 == 3 ? 0 : cur + 1;
    }
#pragma unroll
    for (int i = 0; i < 4; ++i)
#pragma unroll
        for (int j = 0; j < NJ; ++j)
#pragma unroll
            for (int r = 0; r < 4; ++r) {
                int row = row0 + wrow + i * 16 + lhi * 4 + r;
                int col = col0 + wcol + j * 16 + l15;
                float v = acc[i][j][r];
                if (BIAS) v += bias[col];
                if (GELU_) v = 0.5f * v * (1.0f + erff(v * 0.70710678118f));
                if (RESID == 1) v += ((const float*)resid)[(size_t)row * N + col];
                if (RESID == 2) v += bf2f(((const unsigned short*)resid)[(size_t)row * N + col]);
                if (OBF)
                    ((unsigned short*)C)[(size_t)row * N + col] = f2bf(v);
                else
                    ((float*)C)[(size_t)row * N + col] = v;
            }
}

// ---------- V transpose with sigma permutation along kv within each 64-block ----------
// vt[b,h][d][kt*64 + s] = V[kv = kt*64 + sigma(s)][d],  sigma: out = {s5,s2,s4,s3,s1,s0}
__global__ __launch_bounds__(256) void vtrans_kernel(const unsigned short* __restrict__ qkv,
                                                     unsigned short* __restrict__ vt) {
    __shared__ unsigned short t[64 * 72];
    int tid = threadIdx.x;
    int nt = blockIdx.x & 31, h = (blockIdx.x >> 5) & 15, b = blockIdx.x >> 9;
#pragma unroll
    for (int p = 0; p < 2; ++p) {
        int c = tid + p * 256;
        int n = c >> 3, s = (c & 7) * 8;
        *(uint4*)&t[n * 72 + s] =
            *(const uint4*)(qkv + (size_t)(b * SEQ + nt * 64 + n) * 3072 + 2048 + h * 64 + s);
    }
    __syncthreads();
#pragma unroll
    for (int p = 0; p < 2; ++p) {
        int c = tid + p * 256;
        int d = c >> 3, s0 = (c & 7) * 8;
        u16x8 val;
#pragma unroll
        for (int j = 0; j < 8; ++j) {
            int s = s0 + j;
            int sig = (s & 32) | ((s & 4) << 2) | ((s & 24) >> 1) | (s & 3);
            val[j] = t[sig * 72 + d];
        }
        *(u16x8*)(vt + ((size_t)(b * NHEADS + h) * DH + d) * SEQ + nt * 64 + s0) = val;
    }
}

// ---------- flash attention (R6 structure): 16 q/wave, 64 q/block, direct output ----------
__global__ __launch_bounds__(256) void attn_kernel(const unsigned short* __restrict__ qkv,
                                                   const unsigned short* __restrict__ vt,
                                                   unsigned short* __restrict__ o) {
    __shared__ unsigned short Ks[2][64 * 64];
    __shared__ unsigned short Vs[2][64 * 64];
    int tid = threadIdx.x;
    int lane = tid & 63, w = tid >> 6;
    int l15 = lane & 15, lhi = lane >> 4;
    int wg = blockIdx.x;  // 1024 blocks, 4/CU
    int swz = (wg & 7) * 128 + (wg >> 3);  // 128 consecutive per XCD (4 heads' K/V per L2)
    int qt = swz & 31, h = (swz >> 5) & 15, b = swz >> 9;
    // wave w owns q rows [qt*64 + w*16, +16); Q pre-scaled by 0.125*log2e via weights
    const unsigned short* qb =
        qkv + (size_t)(b * SEQ + qt * 64 + w * 16 + l15) * 3072 + h * DH;
    bf16x8 qf0 = *(const bf16x8*)(qb + lhi * 8);
    bf16x8 qf1 = *(const bf16x8*)(qb + 32 + lhi * 8);
    f32x4 zero = {0.f, 0.f, 0.f, 0.f};
    f32x4 oacc[4], lacc = zero;
#pragma unroll
    for (int i = 0; i < 4; ++i) oacc[i] = zero;
    const short one_s = (short)0x3F80;  // bf16 1.0
    bf16x8 ones = {one_s, one_s, one_s, one_s, one_s, one_s, one_s, one_s};
    // staging: dest linear, source 16B-unit XOR-swizzled with row&7
    int srow = tid >> 3;
    int scx = (tid & 7) ^ (srow & 7);
    const unsigned short* kb = qkv + (size_t)b * SEQ * 3072 + 1024 + h * DH;
    const unsigned short* vb = vt + (size_t)(b * NHEADS + h) * DH * SEQ;
    const unsigned short* k0 = kb + (size_t)srow * 3072 + scx * 8;
    const unsigned short* v0 = vb + (size_t)srow * SEQ + scx * 8;
    auto stage = [&](int buf, int kt) {
        unsigned short* lk = &Ks[buf][0] + tid * 8;
        unsigned short* lv = &Vs[buf][0] + tid * 8;
        gld16(k0 + (size_t)kt * 64 * 3072, lk);
        gld16(k0 + ((size_t)kt * 64 + 32) * 3072, lk + 2048);
        gld16(v0 + kt * 64, lv);
        gld16(v0 + (size_t)32 * SEQ + kt * 64, lv + 2048);
    };
    const int NT = SEQ / 64;
    stage(0, 0);
    asm volatile("s_waitcnt vmcnt(0)" ::: "memory");
    __builtin_amdgcn_s_barrier();
    __builtin_amdgcn_sched_barrier(0);
    int kx = l15 & 7;
    for (int kt = 0; kt < NT; ++kt) {
        int cur = kt & 1;
        if (kt + 1 < NT) stage(cur ^ 1, kt + 1);
        const unsigned short* Kc = &Ks[cur][0];
        const unsigned short* Vc = &Vs[cur][0];
        // S^T = K @ Q^T : lane holds S[kv=16nt+4lhi+r][q=l15]
        f32x4 sacc[4];
#pragma unroll
        for (int nt = 0; nt < 4; ++nt) {
            bf16x8 kf0 = *(const bf16x8*)&Kc[(nt * 16 + l15) * 64 + ((lhi ^ kx) * 8)];
            bf16x8 kf1 = *(const bf16x8*)&Kc[(nt * 16 + l15) * 64 + (((4 + lhi) ^ kx) * 8)];
            f32x4 z = __builtin_amdgcn_mfma_f32_16x16x32_bf16(kf0, qf0, zero, 0, 0, 0);
            sacc[nt] = __builtin_amdgcn_mfma_f32_16x16x32_bf16(kf1, qf1, z, 0, 0, 0);
        }
        // P = exp2(S) (scale pre-folded into Q), packed lane-local via sigma-permuted V
        bf16x8 pf[2];
#pragma unroll
        for (int kc = 0; kc < 2; ++kc) {
            union { bf16x8 v; unsigned int u[4]; } pu;
            pu.u[0] = cvt_pk_bf16(fexp2(sacc[2 * kc][0]), fexp2(sacc[2 * kc][1]));
            pu.u[1] = cvt_pk_bf16(fexp2(sacc[2 * kc][2]), fexp2(sacc[2 * kc][3]));
            pu.u[2] = cvt_pk_bf16(fexp2(sacc[2 * kc + 1][0]), fexp2(sacc[2 * kc + 1][1]));
            pu.u[3] = cvt_pk_bf16(fexp2(sacc[2 * kc + 1][2]), fexp2(sacc[2 * kc + 1][3]));
            pf[kc] = pu.v;
        }
        // O^T += V^T @ P^T ; l += ones @ P^T
#pragma unroll
        for (int dt = 0; dt < 4; ++dt)
#pragma unroll
            for (int kc = 0; kc < 2; ++kc) {
                bf16x8 vf = *(const bf16x8*)&Vc[(dt * 16 + l15) * 64 + (((kc * 4 + lhi) ^ kx) * 8)];
                oacc[dt] = __builtin_amdgcn_mfma_f32_16x16x32_bf16(vf, pf[kc], oacc[dt], 0, 0, 0);
            }
        lacc = __builtin_amdgcn_mfma_f32_16x16x32_bf16(ones, pf[0], lacc, 0, 0, 0);
        lacc = __builtin_amdgcn_mfma_f32_16x16x32_bf16(ones, pf[1], lacc, 0, 0, 0);
        __builtin_amdgcn_sched_barrier(0);
        if (kt + 1 < NT) {
            asm volatile("s_waitcnt vmcnt(0)" ::: "memory");
            __builtin_amdgcn_s_barrier();
            __builtin_amdgcn_sched_barrier(0);
        }
    }
    float rl = 1.0f / lacc[0];
    size_t orow = (size_t)(b * SEQ + qt * 64 + w * 16 + l15) * DIM + h * DH;
#pragma unroll
    for (int dt = 0; dt < 4; ++dt) {
        ushort4 st;
        st.x = f2bf(oacc[dt][0] * rl);
        st.y = f2bf(oacc[dt][1] * rl);
        st.z = f2bf(oacc[dt][2] * rl);
        st.w = f2bf(oacc[dt][3] * rl);
        *(ushort4*)(o + orow + dt * 16 + lhi * 4) = st;
    }
}

extern "C" void kernel_launch(void* const* d_in, const int* in_sizes, int n_in,
                              void* d_out, int out_size, void* d_ws, size_t ws_size,
                              hipStream_t stream) {
    (void)in_sizes; (void)n_in; (void)out_size; (void)ws_size;
    const float* x = (const float*)d_in[0];
    const float* w_qkv = (const float*)d_in[1];
    const float* w_out = (const float*)d_in[2];
    const float* b_out = (const float*)d_in[3];
    const float* g1 = (const float*)d_in[4];
    const float* bt1 = (const float*)d_in[5];
    const float* g2 = (const float*)d_in[6];
    const float* bt2 = (const float*)d_in[7];
    const float* w1 = (const float*)d_in[8];
    const float* b1 = (const float*)d_in[9];
    const float* w2 = (const float*)d_in[10];
    const float* b2 = (const float*)d_in[11];
    float* out = (float*)d_out;

    char* ws = (char*)d_ws;
    size_t off = 0;
    auto alloc = [&](size_t bytes) {
        void* p = ws + off;
        off += (bytes + 255) & ~(size_t)255;
        return p;
    };
    const int R = 2 * SEQ;  // 4096 rows
    unsigned short* xl    = (unsigned short*)alloc((size_t)R * DIM * 2);
    unsigned short* wqkvT = (unsigned short*)alloc((size_t)3 * DIM * DIM * 2);
    unsigned short* woutT = (unsigned short*)alloc((size_t)DIM * DIM * 2);
    unsigned short* w1T   = (unsigned short*)alloc((size_t)DIM * DIM * 2);
    unsigned short* w2T   = (unsigned short*)alloc((size_t)DIM * DIM * 2);
    unsigned short* qkvb  = (unsigned short*)alloc((size_t)R * 3 * DIM * 2);
    unsigned short* vtb   = (unsigned short*)alloc((size_t)R * DIM * 2);
    unsigned short* attO  = (unsigned short*)alloc((size_t)R * DIM * 2);
    unsigned short* outb  = (unsigned short*)alloc((size_t)R * DIM * 2);  // residual stream (bf16)
    unsigned short* h2    = (unsigned short*)alloc((size_t)R * DIM * 2);
    unsigned short* ffn1  = (unsigned short*)alloc((size_t)R * DIM * 2);

    const float CS = 0.125f * 1.44269504f;  // attn scale * log2(e), folded into Q weights
    wtrans_ln<<<dim3(128, 32, 5), 256, 0, stream>>>(w_qkv, w_out, w1, w2, wqkvT, woutT, w1T, w2T,
                                                    CS, x, g1, bt1, xl);

    const unsigned int SH_FFN = (3 * 128 * 64 + 3 * 64 * 64) * 2;  // 72 KB
    gemm256_qkv<<<dim3((R / 256) * (3 * DIM / 256)), 512, 0, stream>>>(
        xl, wqkvT, qkvb, R, 3 * DIM, DIM, 3 * DIM / 256);
    vtrans_kernel<<<2 * NHEADS * (SEQ / 64), 256, 0, stream>>>(qkvb, vtb);
    attn_kernel<<<2 * NHEADS * (SEQ / 64), 256, 0, stream>>>(qkvb, vtb, attO);
    gemm_kernel<64, 64, 1, 1, 0, 1><<<dim3((DIM / 64) * (R / 128)), 256, SH_FFN, stream>>>(
        attO, woutT, outb, b_out, x, R, DIM, DIM, DIM / 64);
    ln_bf16<<<R, 256, 0, stream>>>(outb, g2, bt2, h2);
    gemm_kernel<64, 64, 1, 1, 1, 0><<<dim3((DIM / 64) * (R / 128)), 256, SH_FFN, stream>>>(
        h2, w1T, ffn1, b1, nullptr, R, DIM, DIM, DIM / 64);
    gemm_kernel<64, 64, 0, 1, 0, 2><<<dim3((DIM / 64) * (R / 128)), 256, SH_FFN, stream>>>(
        ffn1, w2T, out, b2, outb, R, DIM, DIM, DIM / 64);
}

// Round 17
// 155.195 us; speedup vs baseline: 1.1384x; 1.0129x over previous
//
#include <hip/hip_runtime.h>
#include <math.h>

typedef __attribute__((ext_vector_type(4))) float f32x4;
typedef __attribute__((ext_vector_type(8))) short bf16x8;
typedef __attribute__((ext_vector_type(8))) unsigned short u16x8;

#define DIM 1024
#define SEQ 2048
#define NHEADS 16
#define DH 64

__device__ __forceinline__ unsigned short f2bf(float f) {
    unsigned int u = __builtin_bit_cast(unsigned int, f);
    u += 0x7fffu + ((u >> 16) & 1u);
    return (unsigned short)(u >> 16);
}

__device__ __forceinline__ float bf2f(unsigned short s) {
    unsigned int u = (unsigned int)s << 16;
    return __builtin_bit_cast(float, u);
}

__device__ __forceinline__ unsigned int cvt_pk_bf16(float lo, float hi) {
    unsigned int r;
    asm("v_cvt_pk_bf16_f32 %0, %1, %2" : "=v"(r) : "v"(lo), "v"(hi));
    return r;
}

__device__ __forceinline__ float fexp2(float x) {
    float r;
    asm("v_exp_f32 %0, %1" : "=v"(r) : "v"(x));
    return r;
}

__device__ __forceinline__ void gld16(const unsigned short* g, unsigned short* l) {
    __builtin_amdgcn_global_load_lds((const __attribute__((address_space(1))) void*)g,
                                     (__attribute__((address_space(3))) void*)l, 16, 0, 0);
}

// ---------- weight transposes (z=0..3) + LayerNorm1 (z=4) in one launch ----------
__global__ __launch_bounds__(256) void wtrans_ln(const float* __restrict__ wq,
                                                 const float* __restrict__ wo,
                                                 const float* __restrict__ wf1,
                                                 const float* __restrict__ wf2,
                                                 unsigned short* __restrict__ oq,
                                                 unsigned short* __restrict__ oo,
                                                 unsigned short* __restrict__ of1,
                                                 unsigned short* __restrict__ of2, float sc,
                                                 const float* __restrict__ x,
                                                 const float* __restrict__ g1,
                                                 const float* __restrict__ bt1,
                                                 unsigned short* __restrict__ xl) {
    int z = blockIdx.z;
    int bxi = blockIdx.x;
    int tid = threadIdx.x;
    if (z == 4) {  // LayerNorm over x rows
        int row = blockIdx.y * 128 + bxi;
        const float4* xr = (const float4*)(x + (size_t)row * DIM);
        float4 v = xr[tid];
        float s1 = v.x + v.y + v.z + v.w;
        float s2 = v.x * v.x + v.y * v.y + v.z * v.z + v.w * v.w;
#pragma unroll
        for (int m = 32; m >= 1; m >>= 1) {
            s1 += __shfl_xor(s1, m);
            s2 += __shfl_xor(s2, m);
        }
        __shared__ float r1[4], r2[4];
        int w = tid >> 6;
        if ((tid & 63) == 0) { r1[w] = s1; r2[w] = s2; }
        __syncthreads();
        s1 = r1[0] + r1[1] + r1[2] + r1[3];
        s2 = r2[0] + r2[1] + r2[2] + r2[3];
        float mu = s1 * (1.0f / DIM);
        float var = s2 * (1.0f / DIM) - mu * mu;
        float rstd = rsqrtf(var + 1e-5f);
        float4 g4 = ((const float4*)g1)[tid];
        float4 b4 = ((const float4*)bt1)[tid];
        ushort4 ov;
        ov.x = f2bf((v.x - mu) * rstd * g4.x + b4.x);
        ov.y = f2bf((v.y - mu) * rstd * g4.y + b4.y);
        ov.z = f2bf((v.z - mu) * rstd * g4.z + b4.z);
        ov.w = f2bf((v.w - mu) * rstd * g4.w + b4.w);
        *(ushort4*)(xl + (size_t)row * DIM + tid * 4) = ov;
        return;
    }
    if (bxi >= (z == 0 ? 96 : 32)) return;
    const float* w = z == 0 ? wq : z == 1 ? wo : z == 2 ? wf1 : wf2;
    unsigned short* wt = z == 0 ? oq : z == 1 ? oo : z == 2 ? of1 : of2;
    int N = z == 0 ? 3072 : 1024;
    int scale_n = z == 0 ? 1024 : 0;
    const int K = 1024;
    __shared__ float t[32][33];
    int n0 = bxi * 32, k0 = blockIdx.y * 32;
    int c = tid & 31, rb = tid >> 5;
#pragma unroll
    for (int i = 0; i < 4; ++i) {
        int r = rb + i * 8;
        t[r][c] = w[(size_t)(k0 + r) * N + n0 + c];
    }
    __syncthreads();
#pragma unroll
    for (int i = 0; i < 4; ++i) {
        int r = rb + i * 8;  // N-local
        float v = t[c][r];
        if (n0 + r < scale_n) v *= sc;
        wt[(size_t)(n0 + r) * K + k0 + c] = f2bf(v);
    }
}

// ---------- LayerNorm: bf16 in -> bf16 out ----------
__global__ __launch_bounds__(256) void ln_bf16(const unsigned short* __restrict__ x,
                                               const float* __restrict__ g,
                                               const float* __restrict__ bt,
                                               unsigned short* __restrict__ o) {
    int row = blockIdx.x, tid = threadIdx.x;
    ushort4 v4 = *(const ushort4*)(x + (size_t)row * DIM + tid * 4);
    float vx = bf2f(v4.x), vy = bf2f(v4.y), vz = bf2f(v4.z), vw = bf2f(v4.w);
    float s1 = vx + vy + vz + vw;
    float s2 = vx * vx + vy * vy + vz * vz + vw * vw;
#pragma unroll
    for (int m = 32; m >= 1; m >>= 1) {
        s1 += __shfl_xor(s1, m);
        s2 += __shfl_xor(s2, m);
    }
    __shared__ float r1[4], r2[4];
    int w = tid >> 6;
    if ((tid & 63) == 0) { r1[w] = s1; r2[w] = s2; }
    __syncthreads();
    s1 = r1[0] + r1[1] + r1[2] + r1[3];
    s2 = r2[0] + r2[1] + r2[2] + r2[3];
    float mu = s1 * (1.0f / DIM);
    float var = s2 * (1.0f / DIM) - mu * mu;
    float rstd = rsqrtf(var + 1e-5f);
    float4 g4 = ((const float4*)g)[tid];
    float4 b4 = ((const float4*)bt)[tid];
    ushort4 ov;
    ov.x = f2bf((vx - mu) * rstd * g4.x + b4.x);
    ov.y = f2bf((vy - mu) * rstd * g4.y + b4.y);
    ov.z = f2bf((vz - mu) * rstd * g4.z + b4.z);
    ov.w = f2bf((vw - mu) * rstd * g4.w + b4.w);
    *(ushort4*)(o + (size_t)row * DIM + tid * 4) = ov;
}

// ---------- 256x256 8-wave GEMM for qkv: phase-split, counted-vmcnt ring ----------
// C[M,N] = A[M,K] @ BT[N,K]^T, all bf16. BM=BN=256, BK=64, 512 threads.
// V col-blocks (col0>=2048) write sigma-permuted transposed V to vt instead of C.
__global__ __launch_bounds__(512) void gemm256_qkv(const unsigned short* __restrict__ A,
                                                   const unsigned short* __restrict__ BT,
                                                   unsigned short* __restrict__ C,
                                                   unsigned short* __restrict__ vt,
                                                   int M, int N, int K, int nbx) {
    __shared__ unsigned short SM[65536];  // 128 KB: As[2][16384] | Bs[2][16384]
    unsigned short* As = SM;
    unsigned short* Bs = SM + 32768;
    int tid = threadIdx.x;
    int lane = tid & 63, w = tid >> 6;
    int l15 = lane & 15, lhi = lane >> 4;
    int wr = w >> 2, wc = w & 3;  // 2M x 4N wave grid; per-wave C = 128x64
    int nwg = gridDim.x, wg = blockIdx.x;
    int swz = (wg & 7) * (nwg >> 3) + (wg >> 3);  // XCD-chunked (192 % 8 == 0)
    int bx = swz % nbx, by = swz / nbx;
    int row0 = by * 256, col0 = bx * 256;
    f32x4 zero = {0.f, 0.f, 0.f, 0.f};
    f32x4 acc[8][4];
#pragma unroll
    for (int i = 0; i < 8; ++i)
#pragma unroll
        for (int j = 0; j < 4; ++j) acc[i][j] = zero;
    auto stageA = [&](int slot, int kt) {
#pragma unroll
        for (int p = 0; p < 4; ++p) {
            int u = tid + p * 512;
            int r = u >> 3, cu = u & 7;
            int scu = cu ^ (r & 7);
            gld16(A + (size_t)(row0 + r) * K + kt * 64 + scu * 8, As + slot * 16384 + u * 8);
        }
    };
    auto stageB = [&](int slot, int kt) {
#pragma unroll
        for (int p = 0; p < 4; ++p) {
            int u = tid + p * 512;
            int r = u >> 3, cu = u & 7;
            int scu = cu ^ (r & 7);
            gld16(BT + (size_t)(col0 + r) * K + kt * 64 + scu * 8, Bs + slot * 16384 + u * 8);
        }
    };
    int nk = K / 64;  // 16
    stageB(0, 0);
    stageA(0, 0);
    stageB(1, 1);
    stageA(1, 1);
    asm volatile("s_waitcnt vmcnt(8)" ::: "memory");
    __builtin_amdgcn_s_barrier();
    __builtin_amdgcn_sched_barrier(0);
    for (int t = 0; t < nk; ++t) {
        int cur = t & 1;
        const unsigned short* Ab = As + cur * 16384;
        const unsigned short* Bb = Bs + cur * 16384;
        bf16x8 bfr[4][2];
#pragma unroll
        for (int j = 0; j < 4; ++j)
#pragma unroll
            for (int kk = 0; kk < 2; ++kk) {
                int rr = wc * 64 + j * 16 + l15;
                bfr[j][kk] = *(const bf16x8*)&Bb[rr * 64 + (((kk * 4 + lhi) ^ (rr & 7)) * 8)];
            }
#pragma unroll
        for (int q = 0; q < 4; ++q) {
            bf16x8 af[2][2];
#pragma unroll
            for (int i2 = 0; i2 < 2; ++i2)
#pragma unroll
                for (int kk = 0; kk < 2; ++kk) {
                    int rr = wr * 128 + (q * 2 + i2) * 16 + l15;
                    af[i2][kk] = *(const bf16x8*)&Ab[rr * 64 + (((kk * 4 + lhi) ^ (rr & 7)) * 8)];
                }
#pragma unroll
            for (int kk = 0; kk < 2; ++kk)
#pragma unroll
                for (int i2 = 0; i2 < 2; ++i2)
#pragma unroll
                    for (int j = 0; j < 4; ++j)
                        acc[q * 2 + i2][j] = __builtin_amdgcn_mfma_f32_16x16x32_bf16(
                            af[i2][kk], bfr[j][kk], acc[q * 2 + i2][j], 0, 0, 0);
            if (q == 0) {
                __builtin_amdgcn_sched_barrier(0);
                __builtin_amdgcn_s_barrier();
                __builtin_amdgcn_sched_barrier(0);
                if (t + 2 < nk) stageB(cur, t + 2);
            }
        }
        __builtin_amdgcn_sched_barrier(0);
        __builtin_amdgcn_s_barrier();
        __builtin_amdgcn_sched_barrier(0);
        if (t + 2 < nk) stageA(cur, t + 2);
        if (t + 1 < nk) {
            if (t + 2 < nk)
                asm volatile("s_waitcnt vmcnt(8)" ::: "memory");
            else
                asm volatile("s_waitcnt vmcnt(0)" ::: "memory");
            __builtin_amdgcn_s_barrier();
            __builtin_amdgcn_sched_barrier(0);
        }
    }
    if (col0 >= 2048) {
        // V block: transpose + sigma-permute into vt[b,h][d][n]; skip qkvb write.
        __builtin_amdgcn_sched_barrier(0);
        __syncthreads();  // all waves done with staging LDS
        unsigned short* Ct = SM;  // [256][256] bf16, col XOR'd by ((row>>2)&7)<<3
#pragma unroll
        for (int i = 0; i < 8; ++i)
#pragma unroll
            for (int j = 0; j < 4; ++j)
#pragma unroll
                for (int r = 0; r < 4; ++r) {
                    int row = wr * 128 + i * 16 + lhi * 4 + r;
                    int col = wc * 64 + j * 16 + l15;
                    Ct[row * 256 + (col ^ (((row >> 2) & 7) << 3))] = f2bf(acc[i][j][r]);
                }
        __syncthreads();
        int b = row0 >> 11, n0 = row0 & 2047;
        int h0 = (col0 - 2048) >> 6;  // 4 heads per 256-col tile
        int c = tid >> 1, hf = tid & 1;
        int hl = c >> 6, d = c & 63;
        unsigned short* vrow =
            vt + ((size_t)(b * NHEADS + h0 + hl) * DH + d) * SEQ + n0 + hf * 128;
#pragma unroll
        for (int s8 = 0; s8 < 16; ++s8) {
            u16x8 val;
#pragma unroll
            for (int j = 0; j < 8; ++j) {
                int nn = hf * 128 + s8 * 8 + j;
                int ntl = nn >> 6, s = nn & 63;
                int sig = (s & 32) | ((s & 4) << 2) | ((s & 24) >> 1) | (s & 3);
                int rr = ntl * 64 + sig;
                val[j] = Ct[rr * 256 + (c ^ (((rr >> 2) & 7) << 3))];
            }
            *(u16x8*)(vrow + s8 * 8) = val;
        }
        return;
    }
#pragma unroll
    for (int i = 0; i < 8; ++i)
#pragma unroll
        for (int j = 0; j < 4; ++j)
#pragma unroll
            for (int r = 0; r < 4; ++r) {
                int row = row0 + wr * 128 + i * 16 + lhi * 4 + r;
                int col = col0 + wc * 64 + j * 16 + l15;
                C[(size_t)row * N + col] = f2bf(acc[i][j][r]);
            }
}

// ---------- GEMM, 3-buffer counted-vmcnt pipeline, XOR-swizzled LDS (N=1024 GEMMs) ----------
// RESID: 0=none, 1=f32 resid, 2=bf16 resid.
template <int BN, int BK, int OBF, int BIAS, int GELU_, int RESID>
__global__ __launch_bounds__(256) void gemm_kernel(const unsigned short* __restrict__ A,
                                                   const unsigned short* __restrict__ BT,
                                                   void* __restrict__ C,
                                                   const float* __restrict__ bias,
                                                   const void* __restrict__ resid,
                                                   int M, int N, int K, int nbx) {
    constexpr int U = BK / 8;
    constexpr int NAU = 128 * U;
    constexpr int NBU = BN * U;
    constexpr int PT = (NAU + NBU) / 256;
    constexpr int NJ = BN / 32;
    constexpr int KK = BK / 32;
    extern __shared__ char smem[];
    unsigned short* As = (unsigned short*)smem;
    unsigned short* Bs = As + 3 * 128 * BK;
    int tid = threadIdx.x;
    int lane = tid & 63, w = tid >> 6;
    int l15 = lane & 15, lhi = lane >> 4;
    int nwg = gridDim.x, wg = blockIdx.x;
    int swz = (wg & 7) * (nwg >> 3) + (wg >> 3);
    int bx = swz % nbx, by = swz / nbx;
    int row0 = by * 128, col0 = bx * BN;
    int wrow = (w >> 1) * 64, wcol = (w & 1) * (16 * NJ);
    auto rh = [](int rr) -> int {
        if constexpr (U == 4) return (rr ^ (rr >> 2)) & 3;
        else return rr & (U - 1);
    };
    f32x4 zero = {0.f, 0.f, 0.f, 0.f};
    f32x4 acc[4][NJ];
#pragma unroll
    for (int i = 0; i < 4; ++i)
#pragma unroll
        for (int j = 0; j < NJ; ++j) acc[i][j] = zero;
    auto stage = [&](int buf, int kt) {
#pragma unroll
        for (int p = 0; p < PT; ++p) {
            if (p * 256 < NAU) {
                int u = tid + p * 256;
                int r = u / U, cu = u % U;
                int scu = cu ^ rh(r);
                gld16(A + (size_t)(row0 + r) * K + kt * BK + scu * 8, As + buf * 128 * BK + u * 8);
            } else {
                int ub = tid + p * 256 - NAU;
                int r = ub / U, cu = ub % U;
                int scu = cu ^ rh(r);
                gld16(BT + (size_t)(col0 + r) * K + kt * BK + scu * 8, Bs + buf * BN * BK + ub * 8);
            }
        }
    };
    int nk = K / BK;
    stage(0, 0);
    stage(1, 1);
    asm volatile("s_waitcnt vmcnt(%0)" ::"i"(PT) : "memory");
    __builtin_amdgcn_s_barrier();
    __builtin_amdgcn_sched_barrier(0);
    int cur = 0;
    for (int kt = 0; kt < nk; ++kt) {
        int nxt2 = cur + 2 >= 3 ? cur - 1 : cur + 2;
        if (kt + 2 < nk) stage(nxt2, kt + 2);
        const unsigned short* Ab = As + cur * 128 * BK;
        const unsigned short* Bb = Bs + cur * BN * BK;
        bf16x8 af[4][KK], bfr[NJ][KK];
#pragma unroll
        for (int i = 0; i < 4; ++i)
#pragma unroll
            for (int kk = 0; kk < KK; ++kk) {
                int rr = wrow + i * 16 + l15;
                int up = (kk * 4 + lhi) ^ rh(rr);
                af[i][kk] = *(const bf16x8*)&Ab[rr * BK + up * 8];
            }
#pragma unroll
        for (int j = 0; j < NJ; ++j)
#pragma unroll
            for (int kk = 0; kk < KK; ++kk) {
                int rr = wcol + j * 16 + l15;
                int up = (kk * 4 + lhi) ^ rh(rr);
                bfr[j][kk] = *(const bf16x8*)&Bb[rr * BK + up * 8];
            }
#pragma unroll
        for (int kk = 0; kk < KK; ++kk)
#pragma unroll
            for (int i = 0; i < 4; ++i)
#pragma unroll
                for (int j = 0; j < NJ; ++j)
                    acc[i][j] = __builtin_amdgcn_mfma_f32_16x16x32_bf16(af[i][kk], bfr[j][kk],
                                                                        acc[i][j], 0, 0, 0);
        __builtin_amdgcn_sched_barrier(0);
        if (kt + 1 < nk) {
            if (kt + 2 < nk)
                asm volatile("s_waitcnt vmcnt(%0)" ::"i"(PT) : "memory");
            else
                asm volatile("s_waitcnt vmcnt(0)" ::: "memory");
            __builtin_amdgcn_s_barrier();
            __builtin_amdgcn_sched_barrier(0);
        }
        cur = cur + 1 == 3 ? 0 : cur + 1;
    }
#pragma unroll
    for (int i = 0; i < 4; ++i)
#pragma unroll
        for (int j = 0; j < NJ; ++j)
#pragma unroll
            for (int r = 0; r < 4; ++r) {
                int row = row0 + wrow + i * 16 + lhi * 4 + r;
                int col = col0 + wcol + j * 16 + l15;
                float v = acc[i][j][r];
                if (BIAS) v += bias[col];
                if (GELU_) v = 0.5f * v * (1.0f + erff(v * 0.70710678118f));
                if (RESID == 1) v += ((const float*)resid)[(size_t)row * N + col];
                if (RESID == 2) v += bf2f(((const unsigned short*)resid)[(size_t)row * N + col]);
                if (OBF)
                    ((unsigned short*)C)[(size_t)row * N + col] = f2bf(v);
                else
                    ((float*)C)[(size_t)row * N + col] = v;
            }
}

// ---------- flash attention (R6 structure): 16 q/wave, 64 q/block, direct output ----------
__global__ __launch_bounds__(256) void attn_kernel(const unsigned short* __restrict__ qkv,
                                                   const unsigned short* __restrict__ vt,
                                                   unsigned short* __restrict__ o) {
    __shared__ unsigned short Ks[2][64 * 64];
    __shared__ unsigned short Vs[2][64 * 64];
    int tid = threadIdx.x;
    int lane = tid & 63, w = tid >> 6;
    int l15 = lane & 15, lhi = lane >> 4;
    int wg = blockIdx.x;  // 1024 blocks, 4/CU
    int swz = (wg & 7) * 128 + (wg >> 3);  // 128 consecutive per XCD (4 heads' K/V per L2)
    int qt = swz & 31, h = (swz >> 5) & 15, b = swz >> 9;
    // wave w owns q rows [qt*64 + w*16, +16); Q pre-scaled by 0.125*log2e via weights
    const unsigned short* qb =
        qkv + (size_t)(b * SEQ + qt * 64 + w * 16 + l15) * 3072 + h * DH;
    bf16x8 qf0 = *(const bf16x8*)(qb + lhi * 8);
    bf16x8 qf1 = *(const bf16x8*)(qb + 32 + lhi * 8);
    f32x4 zero = {0.f, 0.f, 0.f, 0.f};
    f32x4 oacc[4], lacc = zero;
#pragma unroll
    for (int i = 0; i < 4; ++i) oacc[i] = zero;
    const short one_s = (short)0x3F80;  // bf16 1.0
    bf16x8 ones = {one_s, one_s, one_s, one_s, one_s, one_s, one_s, one_s};
    // staging: dest linear, source 16B-unit XOR-swizzled with row&7
    int srow = tid >> 3;
    int scx = (tid & 7) ^ (srow & 7);
    const unsigned short* kb = qkv + (size_t)b * SEQ * 3072 + 1024 + h * DH;
    const unsigned short* vb = vt + (size_t)(b * NHEADS + h) * DH * SEQ;
    const unsigned short* k0 = kb + (size_t)srow * 3072 + scx * 8;
    const unsigned short* v0 = vb + (size_t)srow * SEQ + scx * 8;
    auto stage = [&](int buf, int kt) {
        unsigned short* lk = &Ks[buf][0] + tid * 8;
        unsigned short* lv = &Vs[buf][0] + tid * 8;
        gld16(k0 + (size_t)kt * 64 * 3072, lk);
        gld16(k0 + ((size_t)kt * 64 + 32) * 3072, lk + 2048);
        gld16(v0 + kt * 64, lv);
        gld16(v0 + (size_t)32 * SEQ + kt * 64, lv + 2048);
    };
    const int NT = SEQ / 64;
    stage(0, 0);
    asm volatile("s_waitcnt vmcnt(0)" ::: "memory");
    __builtin_amdgcn_s_barrier();
    __builtin_amdgcn_sched_barrier(0);
    int kx = l15 & 7;
    for (int kt = 0; kt < NT; ++kt) {
        int cur = kt & 1;
        if (kt + 1 < NT) stage(cur ^ 1, kt + 1);
        const unsigned short* Kc = &Ks[cur][0];
        const unsigned short* Vc = &Vs[cur][0];
        // S^T = K @ Q^T : lane holds S[kv=16nt+4lhi+r][q=l15]
        f32x4 sacc[4];
#pragma unroll
        for (int nt = 0; nt < 4; ++nt) {
            bf16x8 kf0 = *(const bf16x8*)&Kc[(nt * 16 + l15) * 64 + ((lhi ^ kx) * 8)];
            bf16x8 kf1 = *(const bf16x8*)&Kc[(nt * 16 + l15) * 64 + (((4 + lhi) ^ kx) * 8)];
            f32x4 z = __builtin_amdgcn_mfma_f32_16x16x32_bf16(kf0, qf0, zero, 0, 0, 0);
            sacc[nt] = __builtin_amdgcn_mfma_f32_16x16x32_bf16(kf1, qf1, z, 0, 0, 0);
        }
        // P = exp2(S) (scale pre-folded into Q), packed lane-local via sigma-permuted V
        bf16x8 pf[2];
#pragma unroll
        for (int kc = 0; kc < 2; ++kc) {
            union { bf16x8 v; unsigned int u[4]; } pu;
            pu.u[0] = cvt_pk_bf16(fexp2(sacc[2 * kc][0]), fexp2(sacc[2 * kc][1]));
            pu.u[1] = cvt_pk_bf16(fexp2(sacc[2 * kc][2]), fexp2(sacc[2 * kc][3]));
            pu.u[2] = cvt_pk_bf16(fexp2(sacc[2 * kc + 1][0]), fexp2(sacc[2 * kc + 1][1]));
            pu.u[3] = cvt_pk_bf16(fexp2(sacc[2 * kc + 1][2]), fexp2(sacc[2 * kc + 1][3]));
            pf[kc] = pu.v;
        }
        // O^T += V^T @ P^T ; l += ones @ P^T
#pragma unroll
        for (int dt = 0; dt < 4; ++dt)
#pragma unroll
            for (int kc = 0; kc < 2; ++kc) {
                bf16x8 vf = *(const bf16x8*)&Vc[(dt * 16 + l15) * 64 + (((kc * 4 + lhi) ^ kx) * 8)];
                oacc[dt] = __builtin_amdgcn_mfma_f32_16x16x32_bf16(vf, pf[kc], oacc[dt], 0, 0, 0);
            }
        lacc = __builtin_amdgcn_mfma_f32_16x16x32_bf16(ones, pf[0], lacc, 0, 0, 0);
        lacc = __builtin_amdgcn_mfma_f32_16x16x32_bf16(ones, pf[1], lacc, 0, 0, 0);
        __builtin_amdgcn_sched_barrier(0);
        if (kt + 1 < NT) {
            asm volatile("s_waitcnt vmcnt(0)" ::: "memory");
            __builtin_amdgcn_s_barrier();
            __builtin_amdgcn_sched_barrier(0);
        }
    }
    float rl = 1.0f / lacc[0];
    size_t orow = (size_t)(b * SEQ + qt * 64 + w * 16 + l15) * DIM + h * DH;
#pragma unroll
    for (int dt = 0; dt < 4; ++dt) {
        ushort4 st;
        st.x = f2bf(oacc[dt][0] * rl);
        st.y = f2bf(oacc[dt][1] * rl);
        st.z = f2bf(oacc[dt][2] * rl);
        st.w = f2bf(oacc[dt][3] * rl);
        *(ushort4*)(o + orow + dt * 16 + lhi * 4) = st;
    }
}

extern "C" void kernel_launch(void* const* d_in, const int* in_sizes, int n_in,
                              void* d_out, int out_size, void* d_ws, size_t ws_size,
                              hipStream_t stream) {
    (void)in_sizes; (void)n_in; (void)out_size; (void)ws_size;
    const float* x = (const float*)d_in[0];
    const float* w_qkv = (const float*)d_in[1];
    const float* w_out = (const float*)d_in[2];
    const float* b_out = (const float*)d_in[3];
    const float* g1 = (const float*)d_in[4];
    const float* bt1 = (const float*)d_in[5];
    const float* g2 = (const float*)d_in[6];
    const float* bt2 = (const float*)d_in[7];
    const float* w1 = (const float*)d_in[8];
    const float* b1 = (const float*)d_in[9];
    const float* w2 = (const float*)d_in[10];
    const float* b2 = (const float*)d_in[11];
    float* out = (float*)d_out;

    char* ws = (char*)d_ws;
    size_t off = 0;
    auto alloc = [&](size_t bytes) {
        void* p = ws + off;
        off += (bytes + 255) & ~(size_t)255;
        return p;
    };
    const int R = 2 * SEQ;  // 4096 rows
    unsigned short* xl    = (unsigned short*)alloc((size_t)R * DIM * 2);
    unsigned short* wqkvT = (unsigned short*)alloc((size_t)3 * DIM * DIM * 2);
    unsigned short* woutT = (unsigned short*)alloc((size_t)DIM * DIM * 2);
    unsigned short* w1T   = (unsigned short*)alloc((size_t)DIM * DIM * 2);
    unsigned short* w2T   = (unsigned short*)alloc((size_t)DIM * DIM * 2);
    unsigned short* qkvb  = (unsigned short*)alloc((size_t)R * 3 * DIM * 2);
    unsigned short* vtb   = (unsigned short*)alloc((size_t)R * DIM * 2);
    unsigned short* attO  = (unsigned short*)alloc((size_t)R * DIM * 2);
    unsigned short* outb  = (unsigned short*)alloc((size_t)R * DIM * 2);  // residual stream (bf16)
    unsigned short* h2    = (unsigned short*)alloc((size_t)R * DIM * 2);
    unsigned short* ffn1  = (unsigned short*)alloc((size_t)R * DIM * 2);

    const float CS = 0.125f * 1.44269504f;  // attn scale * log2(e), folded into Q weights
    wtrans_ln<<<dim3(128, 32, 5), 256, 0, stream>>>(w_qkv, w_out, w1, w2, wqkvT, woutT, w1T, w2T,
                                                    CS, x, g1, bt1, xl);

    const unsigned int SH_FFN = (3 * 128 * 64 + 3 * 64 * 64) * 2;  // 72 KB
    gemm256_qkv<<<dim3((R / 256) * (3 * DIM / 256)), 512, 0, stream>>>(
        xl, wqkvT, qkvb, vtb, R, 3 * DIM, DIM, 3 * DIM / 256);
    attn_kernel<<<2 * NHEADS * (SEQ / 64), 256, 0, stream>>>(qkvb, vtb, attO);
    gemm_kernel<64, 64, 1, 1, 0, 1><<<dim3((DIM / 64) * (R / 128)), 256, SH_FFN, stream>>>(
        attO, woutT, outb, b_out, x, R, DIM, DIM, DIM / 64);
    ln_bf16<<<R, 256, 0, stream>>>(outb, g2, bt2, h2);
    gemm_kernel<64, 64, 1, 1, 1, 0><<<dim3((DIM / 64) * (R / 128)), 256, SH_FFN, stream>>>(
        h2, w1T, ffn1, b1, nullptr, R, DIM, DIM, DIM / 64);
    gemm_kernel<64, 64, 0, 1, 0, 2><<<dim3((DIM / 64) * (R / 128)), 256, SH_FFN, stream>>>(
        ffn1, w2T, out, b2, outb, R, DIM, DIM, DIM / 64);
}